// Round 10
// baseline (185.087 us; speedup 1.0000x reference)
//
#include <hip/hip_runtime.h>
#include <math.h>
#include <stdint.h>

#define NA 32          // N_AGENTS
#define SD 2048        // STATE_DIM
#define BT 2048        // B = BS*T
#define NFRG 144       // col frags (2304 padded cols / 16); 128 agent + 12 tail + 4 pad

typedef float floatx4 __attribute__((ext_vector_type(4)));
typedef short bf16x8  __attribute__((ext_vector_type(8)));

__device__ __forceinline__ unsigned short f2bf(float f) {
    union { float f; uint32_t u; } v; v.f = f;
    uint32_t r = v.u + 0x7FFFu + ((v.u >> 16) & 1u);
    return (unsigned short)(r >> 16);
}

__device__ __forceinline__ void stage16(const void* g, void* l) {
    __builtin_amdgcn_global_load_lds(
        (const __attribute__((address_space(1))) void*)g,
        (__attribute__((address_space(3))) void*)l,
        16, 0, 0);
}

// ---- fragment layouts ----
// A-frag (stA):  elem((bt*64+kc)*512 + (quad*16+l16)*8 + j) = st[bt*16+l16][kc*32+quad*8+j]
// B-frag (Wswz): elem(((i*NFRG+f)*2+h)*512 + (quad*16+l16)*8 + j) = W[n=f*16+l16][k=i*64+h*32+quad*8+j]
// C-frag (Ycn, f32): elem((bt*NFRG+f)*256 + (quad*16+l16)*4 + r) = -Y[bt*16+quad*4+r][f*16+l16]

// ---------------- K0: fused input transforms (ast + wswz) ----------------
// blocks 0..2047: st -> A-frag bf16.  blocks 2048..4351: weights -> B-frag.
__global__ __launch_bounds__(256) void k0_prep(const float* __restrict__ st,
                                               unsigned short* __restrict__ stA,
                                               const float* __restrict__ Ww1,
                                               const float* __restrict__ Wwf,
                                               const float* __restrict__ Wb1,
                                               const float* __restrict__ Wv1,
                                               unsigned short* __restrict__ Wswz) {
    const int blk = blockIdx.x;
    const int t = threadIdx.x;
    const int l = t & 63;
    const int quad = l >> 4, l16 = l & 15;

    if (blk < 2048) {               // ---- ast part: grid (16,128) flattened
        const int bx = blk & 15, bt = blk >> 4;
        const int kc = bx * 4 + (t >> 6);   // 0..63
        const float* src = st + (size_t)(bt * 16 + l16) * SD + kc * 32 + quad * 8;
        float4 v0 = *(const float4*)(src);
        float4 v1 = *(const float4*)(src + 4);
        ushort4 o0, o1;
        o0.x = f2bf(v0.x); o0.y = f2bf(v0.y); o0.z = f2bf(v0.z); o0.w = f2bf(v0.w);
        o1.x = f2bf(v1.x); o1.y = f2bf(v1.y); o1.z = f2bf(v1.z); o1.w = f2bf(v1.w);
        unsigned short* dst = stA + ((size_t)bt * 64 + kc) * 512 + l * 8;
        *(ushort4*)(dst)     = o0;
        *(ushort4*)(dst + 4) = o1;
    } else {                        // ---- wswz part: grid (72,32) flattened
        const int b2 = blk - 2048;
        const int bx = b2 % 72, i = b2 / 72;        // i = k-chunk 0..31
        const int f = bx * 2 + (t >> 7);            // frag 0..143
        const int h = (t >> 6) & 1;
        const int n = f * 16 + l16;

        const float* src; int ld, nr = 0;
        if (f < 128)      { src = Ww1; ld = 2048; nr = n; }
        else if (f < 132) { src = Wwf; ld = 64;   nr = n - 2048; }
        else if (f < 136) { src = Wb1; ld = 64;   nr = n - 2112; }
        else if (f < 140) { src = Wv1; ld = 64;   nr = n - 2176; }
        else              { src = nullptr; ld = 64; }

        const int k0 = i * 64 + h * 32 + quad * 8;
        unsigned short vals[8];
        #pragma unroll
        for (int j = 0; j < 8; j++)
            vals[j] = src ? f2bf(src[(size_t)(k0 + j) * ld + nr]) : (unsigned short)0;

        unsigned short* dst = Wswz + (((size_t)i * NFRG + f) * 2 + h) * 512 + l * 8;
        ushort4 o0 = {vals[0], vals[1], vals[2], vals[3]};
        ushort4 o1 = {vals[4], vals[5], vals[6], vals[7]};
        *(ushort4*)(dst)     = o0;
        *(ushort4*)(dst + 4) = o1;
    }
}

// ---------------- K1: Ycn = -(st @ Wcat + bias), LDS-staged tiles --------
// R5-proven version (A and B both global_load_lds-staged, 48 KB, one
// __syncthreads/iter). R6 lesson: register-streaming A regressed (-5 us)
// — the A global loads land on the barrier critical path. Keep as-is.
__global__ __launch_bounds__(256) void k1_gemm(const unsigned short* __restrict__ stA,
                                               const unsigned short* __restrict__ Wswz,
                                               const float* __restrict__ bw1,
                                               const float* __restrict__ bwf,
                                               const float* __restrict__ bb1,
                                               const float* __restrict__ bv1,
                                               float* __restrict__ Ycn)
{
    const int t = threadIdx.x;
    const int m0t = blockIdx.x * 4;   // btile base (64 rows)
    const int n0f = blockIdx.y * 8;   // frag base (128 cols)
    const int wid = t >> 6, lane = t & 63;
    const int wm = wid & 1, wn = wid >> 1;
    const int l16 = lane & 15;

    __shared__ unsigned short As[2][2][4][512];   // [buf][kk][btile][512] = 16 KB
    __shared__ unsigned short Bs[2][2][8][512];   // [buf][kk][frag ][512] = 32 KB

    floatx4 acc[2][4];
    #pragma unroll
    for (int i = 0; i < 2; i++)
        #pragma unroll
        for (int j = 0; j < 4; j++) acc[i][j] = (floatx4)0.f;

    // stage iteration 'it' (kc = it*2, it*2+1) into buffer buf.
    // 24 chunks of 1 KB; this wave issues chunks c = wid*6 .. wid*6+5.
    auto stage = [&](int it, int buf) {
        #pragma unroll
        for (int j = 0; j < 6; j++) {
            const int c   = wid * 6 + j;        // 0..23
            const int kk  = c / 12;             // 0..1
            const int rem = c % 12;
            if (rem < 4) {
                const unsigned short* gp = stA
                    + ((size_t)(m0t + rem) * 64 + (it * 2 + kk)) * 512 + lane * 8;
                stage16(gp, &As[buf][kk][rem][0]);
            } else {
                const int f = rem - 4;          // 0..7
                const unsigned short* gp = Wswz
                    + (((size_t)it * NFRG + (n0f + f)) * 2 + kk) * 512 + lane * 8;
                stage16(gp, &Bs[buf][kk][f][0]);
            }
        }
    };

    stage(0, 0);
    __syncthreads();

    for (int it = 0; it < 32; it++) {
        const int buf = it & 1;
        if (it < 31) stage(it + 1, buf ^ 1);
        #pragma unroll
        for (int kk = 0; kk < 2; kk++) {
            bf16x8 a0 = *(const bf16x8*)&As[buf][kk][wm * 2 + 0][lane * 8];
            bf16x8 a1 = *(const bf16x8*)&As[buf][kk][wm * 2 + 1][lane * 8];
            bf16x8 b[4];
            #pragma unroll
            for (int nf = 0; nf < 4; nf++)
                b[nf] = *(const bf16x8*)&Bs[buf][kk][wn * 4 + nf][lane * 8];
            #pragma unroll
            for (int nf = 0; nf < 4; nf++) {
                acc[0][nf] = __builtin_amdgcn_mfma_f32_16x16x32_bf16(a0, b[nf], acc[0][nf], 0, 0, 0);
                acc[1][nf] = __builtin_amdgcn_mfma_f32_16x16x32_bf16(a1, b[nf], acc[1][nf], 0, 0, 0);
            }
        }
        __syncthreads();
    }

    #pragma unroll
    for (int mf = 0; mf < 2; mf++)
        #pragma unroll
        for (int nf = 0; nf < 4; nf++) {
            const int f  = n0f + wn * 4 + nf;
            const int bt = m0t + wm * 2 + mf;
            const int n  = f * 16 + l16;
            float bias;
            if (f < 128)      bias = bw1[n];
            else if (f < 132) bias = bwf[n - 2048];
            else if (f < 136) bias = bb1[n - 2112];
            else if (f < 140) bias = bv1[n - 2176];
            else              bias = 0.f;
            floatx4 o;
            #pragma unroll
            for (int r = 0; r < 4; r++) o[r] = -(acc[mf][nf][r] + bias);
            *(floatx4*)(Ycn + ((size_t)bt * NFRG + f) * 256 + lane * 4) = o;
        }
}

// ---------------- K3: q1[i][b] (+ q_tot on elected block), staged W ------
// R9: occupancy was grid-pinned at 8 waves/CU (512 blocks x 4 waves);
// every barrier drain had only 1 other block for cover. Split the mask
// PAIR -> one mask per block: grid 32x32 = 1024 blocks = 4 blocks/CU =
// 16 waves/CU (4/SIMD). Per-wave work halves (8 MFMA + 32 VALU/group);
// Ycn C-init sharing is lost (Ycn L2 traffic 295->590 MB, still <=75%
// of L2 ceiling) but latency cover doubles. Keep the proven R1 loop
// (stage -> compute -> __syncthreads; R2-R4: do NOT re-pipeline).
// dotot election p == btg: bijective over btg, XCD-spread (33*btg % 8).
__global__ __launch_bounds__(256, 4) void k3_q1(
    const unsigned short* __restrict__ stA, const float* __restrict__ qs,
    const unsigned short* __restrict__ Wswz, const float* __restrict__ Wv2,
    const float* __restrict__ bv2, const float* __restrict__ Ycn,
    float* __restrict__ q1, float* __restrict__ qtot)
{
    const int p   = blockIdx.x;          // mask 0..31
    const int btg = blockIdx.y;          // bt group of 4
    const int t = threadIdx.x;
    const int w = t >> 6, lane = t & 63;
    const int bt = btg * 4 + w;
    const int quad = lane >> 4, l16 = lane & 15;
    const bool dotot = (p == btg);

    __shared__ unsigned short Wl[2][4][2][512];     // [buf][nf][half][512] = 16 KB
    __shared__ float qs_s[4][16][33];               // per-wave qs tile

    // qs into LDS (per wave)
    {
        int b = lane >> 2, a0 = (lane & 3) * 8;
        const float* src = qs + (size_t)(bt * 16 + b) * NA + a0;
        #pragma unroll
        for (int u = 0; u < 8; u++) qs_s[w][b][a0 + u] = src[u];
    }

    // A fragments (agent-p k-chunk of st)
    bf16x8 A0 = *(const bf16x8*)(stA + ((size_t)bt * 64 + 2 * p + 0) * 512 + lane * 8);
    bf16x8 A1 = *(const bf16x8*)(stA + ((size_t)bt * 64 + 2 * p + 1) * 512 + lane * 8);

    const float* Yb = Ycn + (size_t)bt * NFRG * 256 + lane * 4;

    // stage frag-group fg (frags fg*4..fg*4+3) into buffer buf.
    // 8 chunks of 1 KB; this wave issues chunks c = w*2, w*2+1.
    auto stage = [&](int fg, int buf) {
        #pragma unroll
        for (int j = 0; j < 2; j++) {
            const int c  = w * 2 + j;          // 0..7
            const int nf = c >> 1;
            const int h  = c & 1;
            const unsigned short* g = Wswz
                + ((size_t)(p * NFRG + fg * 4 + nf) * 2 + h) * 512 + lane * 8;
            stage16(g, &Wl[buf][nf][h][0]);
        }
    };

    floatx4 yv[4], yn[4], acc[4];

    auto wmfma = [&](int buf) {
        #pragma unroll
        for (int nf = 0; nf < 4; nf++) {
            bf16x8 w0 = *(const bf16x8*)&Wl[buf][nf][0][lane * 8];
            bf16x8 w1 = *(const bf16x8*)&Wl[buf][nf][1][lane * 8];
            floatx4 a = __builtin_amdgcn_mfma_f32_16x16x32_bf16(A0, w0, yv[nf], 0, 0, 0);
            acc[nf]   = __builtin_amdgcn_mfma_f32_16x16x32_bf16(A1, w1, a, 0, 0, 0);
        }
    };

    floatx4 hid[4];
    #pragma unroll
    for (int nf = 0; nf < 4; nf++) hid[nf] = (floatx4)0.f;

    floatx4 hidT[4], wffT[4], b1fT[4], vaccT = (floatx4)0.f;
    #pragma unroll
    for (int nf = 0; nf < 4; nf++) hidT[nf] = (floatx4)0.f;

    // prologue: stage group 0, prefetch Ycn group 0
    stage(0, 0);
    #pragma unroll
    for (int nf = 0; nf < 4; nf++) yv[nf] = *(const floatx4*)(Yb + (size_t)nf * 256);
    __syncthreads();

    // main agent loop: groups 0..31 (agents)
    for (int fg = 0; fg < 32; fg++) {
        const int cur = fg & 1;
        stage(fg + 1, cur ^ 1);
        {
            const float* yp = Yb + (size_t)(fg + 1) * 4 * 256;
            #pragma unroll
            for (int nf = 0; nf < 4; nf++) yn[nf] = *(const floatx4*)(yp + (size_t)nf * 256);
        }
        wmfma(cur);
        float qv[4];
        #pragma unroll
        for (int r = 0; r < 4; r++) qv[r] = qs_s[w][quad * 4 + r][fg];
        #pragma unroll
        for (int nf = 0; nf < 4; nf++)
            #pragma unroll
            for (int r = 0; r < 4; r++)
                hid[nf][r] += qv[r] * fabsf(acc[nf][r]);
        if (dotot) {
            #pragma unroll
            for (int nf = 0; nf < 4; nf++)
                #pragma unroll
                for (int r = 0; r < 4; r++)
                    hidT[nf][r] += qv[r] * fabsf(yv[nf][r]);
        }
        #pragma unroll
        for (int nf = 0; nf < 4; nf++) yv[nf] = yn[nf];
        __syncthreads();
    }

    floatx4 wff[4], b1f[4], vacc;

    // group 32: wf frags (128..131)   [uses buf 0; fg=31 staged into buf 0]
    {
        stage(33, 1);
        {
            const float* yp = Yb + (size_t)33 * 4 * 256;
            #pragma unroll
            for (int nf = 0; nf < 4; nf++) yn[nf] = *(const floatx4*)(yp + (size_t)nf * 256);
        }
        wmfma(0);
        #pragma unroll
        for (int nf = 0; nf < 4; nf++)
            #pragma unroll
            for (int r = 0; r < 4; r++) wff[nf][r] = fabsf(acc[nf][r]);
        if (dotot) {
            #pragma unroll
            for (int nf = 0; nf < 4; nf++)
                #pragma unroll
                for (int r = 0; r < 4; r++) wffT[nf][r] = fabsf(yv[nf][r]);
        }
        #pragma unroll
        for (int nf = 0; nf < 4; nf++) yv[nf] = yn[nf];
        __syncthreads();
    }
    // group 33: b1 frags (132..135)
    {
        stage(34, 0);
        {
            const float* yp = Yb + (size_t)34 * 4 * 256;
            #pragma unroll
            for (int nf = 0; nf < 4; nf++) yn[nf] = *(const floatx4*)(yp + (size_t)nf * 256);
        }
        wmfma(1);
        #pragma unroll
        for (int nf = 0; nf < 4; nf++)
            #pragma unroll
            for (int r = 0; r < 4; r++) b1f[nf][r] = -acc[nf][r];
        if (dotot) {
            #pragma unroll
            for (int nf = 0; nf < 4; nf++)
                #pragma unroll
                for (int r = 0; r < 4; r++) b1fT[nf][r] = -yv[nf][r];
        }
        #pragma unroll
        for (int nf = 0; nf < 4; nf++) yv[nf] = yn[nf];
        __syncthreads();
    }
    // group 34: v frags (136..139)
    {
        wmfma(0);
        float wv2f[4];
        #pragma unroll
        for (int nf = 0; nf < 4; nf++) wv2f[nf] = Wv2[nf * 16 + l16];
        vacc = (floatx4)0.f;
        #pragma unroll
        for (int nf = 0; nf < 4; nf++)
            #pragma unroll
            for (int r = 0; r < 4; r++)
                vacc[r] += fmaxf(-acc[nf][r], 0.f) * wv2f[nf];
        if (dotot) {
            #pragma unroll
            for (int nf = 0; nf < 4; nf++)
                #pragma unroll
                for (int r = 0; r < 4; r++)
                    vaccT[r] += fmaxf(-yv[nf][r], 0.f) * wv2f[nf];
        }
    }

    const float bv2v = bv2[0];
    #pragma unroll
    for (int r = 0; r < 4; r++) {
        float s = vacc[r];
        #pragma unroll
        for (int nf = 0; nf < 4; nf++) {
            float h = hid[nf][r] + b1f[nf][r];
            h = h > 0.f ? h : expm1f(h);
            s += h * wff[nf][r];
        }
        s += __shfl_xor(s, 1); s += __shfl_xor(s, 2);
        s += __shfl_xor(s, 4); s += __shfl_xor(s, 8);
        if (l16 == 0) q1[(size_t)p * BT + bt * 16 + quad * 4 + r] = s + bv2v;
    }

    if (dotot) {
        #pragma unroll
        for (int r = 0; r < 4; r++) {
            float s = vaccT[r];
            #pragma unroll
            for (int nf = 0; nf < 4; nf++) {
                float h = hidT[nf][r] + b1fT[nf][r];
                h = h > 0.f ? h : expm1f(h);
                s += h * wffT[nf][r];
            }
            s += __shfl_xor(s, 1); s += __shfl_xor(s, 2);
            s += __shfl_xor(s, 4); s += __shfl_xor(s, 8);
            if (l16 == 0) qtot[bt * 16 + quad * 4 + r] = s + bv2v;
        }
    }
}

// ---------------- K4: wc + final mix (q_tot precomputed by k3) -----------
// R7: pass-1 (full Ycn sweep + reduction, existed only to produce q_tot)
// removed; qt is loaded from qtot[]. Remaining: tail frags, wc, pass 2.
__global__ __launch_bounds__(256) void k4_final(
    const float* __restrict__ qs, const float* __restrict__ Ycn,
    const float* __restrict__ q1, const float* __restrict__ qtot,
    const float* __restrict__ Wv2, const float* __restrict__ bv2,
    float* __restrict__ out)
{
    const int bt = blockIdx.x;
    __shared__ float qs_s[16][33];
    __shared__ float qw_s[16][33];
    __shared__ float hidp[4][16][64];
    __shared__ float wfb[16][64], b1b[16][64], vb[16][64];
    __shared__ float qt[16];

    const int t = threadIdx.x, w = t >> 6, lane = t & 63;
    const int quad = lane >> 4, l16 = lane & 15;
    const float bv2v = bv2[0];

    {
        int l = t * 2;
        float2 v = *(const float2*)&qs[(size_t)(bt * 16 + (l >> 5)) * NA + (l & 31)];
        qs_s[l >> 5][(l & 31) + 0] = v.x;
        qs_s[l >> 5][(l & 31) + 1] = v.y;
    }
    if (t < 16) qt[t] = qtot[bt * 16 + t];

    const float* Yb = Ycn + (size_t)bt * NFRG * 256;

    // tail frags: 3 per wave -> wfb / b1b / vb
    #pragma unroll
    for (int fi = 0; fi < 3; fi++) {
        const int nft = w * 3 + fi;
        floatx4 c = *(const floatx4*)(Yb + (size_t)(128 + nft) * 256 + lane * 4);
        const int e = (nft & 3) * 16 + l16;
        #pragma unroll
        for (int r = 0; r < 4; r++) {
            int b = quad * 4 + r;
            if (nft < 4)      wfb[b][e] = fabsf(c[r]);
            else if (nft < 8) b1b[b][e] = -c[r];
            else              vb[b][e]  = fmaxf(-c[r], 0.f) * Wv2[e];
        }
    }
    __syncthreads();

    // wc: thread (w,quad,l16) -> row rr = w*4+quad, agents 2*l16, 2*l16+1
    {
        const int rr = w * 4 + quad;
        float qtv = qt[rr];
        float d0 = fabsf(qtv - q1[(size_t)(2 * l16 + 0) * BT + bt * 16 + rr]);
        float d1 = fabsf(qtv - q1[(size_t)(2 * l16 + 1) * BT + bt * 16 + rr]);
        float ss = d0 * d0 + d1 * d1;
        ss += __shfl_xor(ss, 1); ss += __shfl_xor(ss, 2);
        ss += __shfl_xor(ss, 4); ss += __shfl_xor(ss, 8);
        float inv = 1.f / fmaxf(sqrtf(ss), 1e-12f);
        qw_s[rr][2 * l16 + 0] = qs_s[rr][2 * l16 + 0] * d0 * inv;
        qw_s[rr][2 * l16 + 1] = qs_s[rr][2 * l16 + 1] * d1 * inv;
    }
    __syncthreads();

    // pass 2: hid with qs*wc
    floatx4 hid2[4];
    #pragma unroll
    for (int nf = 0; nf < 4; nf++) hid2[nf] = (floatx4)0.f;
    for (int ia = 0; ia < 8; ia++) {
        const int a = w * 8 + ia;
        const float* yp = Yb + (size_t)(a * 4) * 256 + lane * 4;
        float qv[4];
        #pragma unroll
        for (int r = 0; r < 4; r++) qv[r] = qw_s[quad * 4 + r][a];
        #pragma unroll
        for (int nf = 0; nf < 4; nf++) {
            floatx4 c = *(const floatx4*)(yp + nf * 256);
            #pragma unroll
            for (int r = 0; r < 4; r++) hid2[nf][r] += qv[r] * fabsf(c[r]);
        }
    }
    #pragma unroll
    for (int nf = 0; nf < 4; nf++)
        #pragma unroll
        for (int r = 0; r < 4; r++)
            hidp[w][quad * 4 + r][nf * 16 + l16] = hid2[nf][r];
    __syncthreads();

    #pragma unroll
    for (int bb = 0; bb < 4; bb++) {
        int b = w * 4 + bb;
        float h = hidp[0][b][lane] + hidp[1][b][lane]
                + hidp[2][b][lane] + hidp[3][b][lane] + b1b[b][lane];
        h = h > 0.f ? h : expm1f(h);
        float val = h * wfb[b][lane] + vb[b][lane];
        #pragma unroll
        for (int off = 32; off > 0; off >>= 1) val += __shfl_xor(val, off);
        if (lane == 0) out[bt * 16 + b] = val + bv2v;
    }
}

extern "C" void kernel_launch(void* const* d_in, const int* in_sizes, int n_in,
                              void* d_out, int out_size, void* d_ws, size_t ws_size,
                              hipStream_t stream) {
    const float* qs  = (const float*)d_in[0];
    const float* st  = (const float*)d_in[1];
    const float* Ww1 = (const float*)d_in[2];
    const float* bw1 = (const float*)d_in[3];
    const float* Wwf = (const float*)d_in[4];
    const float* bwf = (const float*)d_in[5];
    const float* Wb1 = (const float*)d_in[6];
    const float* bb1 = (const float*)d_in[7];
    const float* Wv1 = (const float*)d_in[8];
    const float* bv1 = (const float*)d_in[9];
    const float* Wv2 = (const float*)d_in[10];
    const float* bv2 = (const float*)d_in[11];
    float* out = (float*)d_out;

    // workspace (~37 MB, same footprint as proven layout; old bcat slot
    // (2304 f32) reused as qtot (2048 f32) — no footprint change)
    float* Ycn           = (float*)d_ws;                           // 128*144*256 f32 = 18.87 MB
    unsigned short* stA  = (unsigned short*)(Ycn + (size_t)128 * NFRG * 256); // 8.39 MB
    unsigned short* Wswz = stA + (size_t)SD * SD;                  // 32*144*1024 bf16 = 9.44 MB
    float* qtot          = (float*)(Wswz + (size_t)32 * NFRG * 1024); // 2048 f32 (ex-bcat slot)
    float* q1v           = qtot + NFRG * 16;                       // 32*2048 f32

    k0_prep<<<4352, 256, 0, stream>>>(st, stA, Ww1, Wwf, Wb1, Wv1, Wswz);

    k1_gemm<<<dim3(BT / 64, NFRG / 8), 256, 0, stream>>>(stA, Wswz, bw1, bwf, bb1, bv1, Ycn);
    k3_q1  <<<dim3(NA, 32), 256, 0, stream>>>(stA, qs, Wswz, Wv2, bv2, Ycn, q1v, qtot);
    k4_final<<<BT / 16, 256, 0, stream>>>(qs, Ycn, q1v, qtot, Wv2, bv2, out);
}

// Round 11
// 184.508 us; speedup vs baseline: 1.0031x; 1.0031x over previous
//
#include <hip/hip_runtime.h>
#include <math.h>
#include <stdint.h>

#define NA 32          // N_AGENTS
#define SD 2048        // STATE_DIM
#define BT 2048        // B = BS*T
#define NFRG 144       // col frags (2304 padded cols / 16); 128 agent + 12 tail + 4 pad

typedef float floatx4 __attribute__((ext_vector_type(4)));
typedef short bf16x8  __attribute__((ext_vector_type(8)));

__device__ __forceinline__ unsigned short f2bf(float f) {
    union { float f; uint32_t u; } v; v.f = f;
    uint32_t r = v.u + 0x7FFFu + ((v.u >> 16) & 1u);
    return (unsigned short)(r >> 16);
}

__device__ __forceinline__ void stage16(const void* g, void* l) {
    __builtin_amdgcn_global_load_lds(
        (const __attribute__((address_space(1))) void*)g,
        (__attribute__((address_space(3))) void*)l,
        16, 0, 0);
}

// ---- fragment layouts ----
// A-frag (stA):  elem((bt*64+kc)*512 + (quad*16+l16)*8 + j) = st[bt*16+l16][kc*32+quad*8+j]
// B-frag (Wswz): elem(((i*NFRG+f)*2+h)*512 + (quad*16+l16)*8 + j) = W[n=f*16+l16][k=i*64+h*32+quad*8+j]
// C-frag (Ycn, f32): elem((bt*NFRG+f)*256 + (quad*16+l16)*4 + r) = -Y[bt*16+quad*4+r][f*16+l16]

// ---------------- K0: fused input transforms (ast + wswz) ----------------
// blocks 0..2047: st -> A-frag bf16.  blocks 2048..4351: weights -> B-frag.
__global__ __launch_bounds__(256) void k0_prep(const float* __restrict__ st,
                                               unsigned short* __restrict__ stA,
                                               const float* __restrict__ Ww1,
                                               const float* __restrict__ Wwf,
                                               const float* __restrict__ Wb1,
                                               const float* __restrict__ Wv1,
                                               unsigned short* __restrict__ Wswz) {
    const int blk = blockIdx.x;
    const int t = threadIdx.x;
    const int l = t & 63;
    const int quad = l >> 4, l16 = l & 15;

    if (blk < 2048) {               // ---- ast part: grid (16,128) flattened
        const int bx = blk & 15, bt = blk >> 4;
        const int kc = bx * 4 + (t >> 6);   // 0..63
        const float* src = st + (size_t)(bt * 16 + l16) * SD + kc * 32 + quad * 8;
        float4 v0 = *(const float4*)(src);
        float4 v1 = *(const float4*)(src + 4);
        ushort4 o0, o1;
        o0.x = f2bf(v0.x); o0.y = f2bf(v0.y); o0.z = f2bf(v0.z); o0.w = f2bf(v0.w);
        o1.x = f2bf(v1.x); o1.y = f2bf(v1.y); o1.z = f2bf(v1.z); o1.w = f2bf(v1.w);
        unsigned short* dst = stA + ((size_t)bt * 64 + kc) * 512 + l * 8;
        *(ushort4*)(dst)     = o0;
        *(ushort4*)(dst + 4) = o1;
    } else {                        // ---- wswz part: grid (72,32) flattened
        const int b2 = blk - 2048;
        const int bx = b2 % 72, i = b2 / 72;        // i = k-chunk 0..31
        const int f = bx * 2 + (t >> 7);            // frag 0..143
        const int h = (t >> 6) & 1;
        const int n = f * 16 + l16;

        const float* src; int ld, nr = 0;
        if (f < 128)      { src = Ww1; ld = 2048; nr = n; }
        else if (f < 132) { src = Wwf; ld = 64;   nr = n - 2048; }
        else if (f < 136) { src = Wb1; ld = 64;   nr = n - 2112; }
        else if (f < 140) { src = Wv1; ld = 64;   nr = n - 2176; }
        else              { src = nullptr; ld = 64; }

        const int k0 = i * 64 + h * 32 + quad * 8;
        unsigned short vals[8];
        #pragma unroll
        for (int j = 0; j < 8; j++)
            vals[j] = src ? f2bf(src[(size_t)(k0 + j) * ld + nr]) : (unsigned short)0;

        unsigned short* dst = Wswz + (((size_t)i * NFRG + f) * 2 + h) * 512 + l * 8;
        ushort4 o0 = {vals[0], vals[1], vals[2], vals[3]};
        ushort4 o1 = {vals[4], vals[5], vals[6], vals[7]};
        *(ushort4*)(dst)     = o0;
        *(ushort4*)(dst + 4) = o1;
    }
}

// ---------------- K1: Ycn = -(st @ Wcat + bias), 128x128 tile ------------
// R10: 64x128/4-wave -> 128x128/8-wave. 576 -> 288 blocks: per-CU
// barrier-iteration count halves (the per-iter vmcnt(0) drain was the
// bound, as in k3), staging bytes per output elem 3 -> 2 B. All 288
// blocks co-resident (64 KB LDS -> 2 blocks/CU capacity). Loop stays
// the proven stage -> compute -> __syncthreads form (R2-R4: do NOT
// hand-pipeline). Bias computed inline.
__global__ __launch_bounds__(512) void k1_gemm(const unsigned short* __restrict__ stA,
                                               const unsigned short* __restrict__ Wswz,
                                               const float* __restrict__ bw1,
                                               const float* __restrict__ bwf,
                                               const float* __restrict__ bb1,
                                               const float* __restrict__ bv1,
                                               float* __restrict__ Ycn)
{
    const int t = threadIdx.x;
    const int m0t = blockIdx.x * 8;   // btile base (128 rows)
    const int n0f = blockIdx.y * 8;   // frag base (128 cols)
    const int wid = t >> 6, lane = t & 63;
    const int wm = wid & 3, wn = wid >> 2;
    const int l16 = lane & 15;

    __shared__ unsigned short As[2][2][8][512];   // [buf][kk][btile][512] = 32 KB
    __shared__ unsigned short Bs[2][2][8][512];   // [buf][kk][frag ][512] = 32 KB

    floatx4 acc[2][4];
    #pragma unroll
    for (int i = 0; i < 2; i++)
        #pragma unroll
        for (int j = 0; j < 4; j++) acc[i][j] = (floatx4)0.f;

    // stage iteration 'it' (kc = it*2, it*2+1) into buffer buf.
    // 32 chunks of 1 KB; this wave issues chunks c = wid*4 .. wid*4+3.
    auto stage = [&](int it, int buf) {
        #pragma unroll
        for (int j = 0; j < 4; j++) {
            const int c   = wid * 4 + j;        // 0..31
            const int kk  = c >> 4;             // 0..1
            const int rem = c & 15;
            if (rem < 8) {
                const unsigned short* gp = stA
                    + ((size_t)(m0t + rem) * 64 + (it * 2 + kk)) * 512 + lane * 8;
                stage16(gp, &As[buf][kk][rem][0]);
            } else {
                const int f = rem - 8;          // 0..7
                const unsigned short* gp = Wswz
                    + (((size_t)it * NFRG + (n0f + f)) * 2 + kk) * 512 + lane * 8;
                stage16(gp, &Bs[buf][kk][f][0]);
            }
        }
    };

    stage(0, 0);
    __syncthreads();

    for (int it = 0; it < 32; it++) {
        const int buf = it & 1;
        if (it < 31) stage(it + 1, buf ^ 1);
        #pragma unroll
        for (int kk = 0; kk < 2; kk++) {
            bf16x8 a0 = *(const bf16x8*)&As[buf][kk][wm * 2 + 0][lane * 8];
            bf16x8 a1 = *(const bf16x8*)&As[buf][kk][wm * 2 + 1][lane * 8];
            bf16x8 b[4];
            #pragma unroll
            for (int nf = 0; nf < 4; nf++)
                b[nf] = *(const bf16x8*)&Bs[buf][kk][wn * 4 + nf][lane * 8];
            #pragma unroll
            for (int nf = 0; nf < 4; nf++) {
                acc[0][nf] = __builtin_amdgcn_mfma_f32_16x16x32_bf16(a0, b[nf], acc[0][nf], 0, 0, 0);
                acc[1][nf] = __builtin_amdgcn_mfma_f32_16x16x32_bf16(a1, b[nf], acc[1][nf], 0, 0, 0);
            }
        }
        __syncthreads();
    }

    #pragma unroll
    for (int mf = 0; mf < 2; mf++)
        #pragma unroll
        for (int nf = 0; nf < 4; nf++) {
            const int f  = n0f + wn * 4 + nf;
            const int bt = m0t + wm * 2 + mf;
            const int n  = f * 16 + l16;
            float bias;
            if (f < 128)      bias = bw1[n];
            else if (f < 132) bias = bwf[n - 2048];
            else if (f < 136) bias = bb1[n - 2112];
            else if (f < 140) bias = bv1[n - 2176];
            else              bias = 0.f;
            floatx4 o;
            #pragma unroll
            for (int r = 0; r < 4; r++) o[r] = -(acc[mf][nf][r] + bias);
            *(floatx4*)(Ycn + ((size_t)bt * NFRG + f) * 256 + lane * 4) = o;
        }
}

// ---------------- K3: q1[i][b] (+ q_tot on elected block), staged W ------
// R8-proven version (best total 180.0): mask-PAIR per block, 512 blocks,
// stage -> compute -> __syncthreads (R2-R4: do NOT re-pipeline).
// R9 lesson: splitting the pair (2x occupancy) was a wash on k3 and
// regressed the total via scattered q1 write amplification. k3's floor
// in this decomposition is ~47-49 us — frozen.
// dotot election p == (btg & 15): bijective, XCD-spread (4 per XCD).
__global__ __launch_bounds__(256) void k3_q1(
    const unsigned short* __restrict__ stA, const float* __restrict__ qs,
    const unsigned short* __restrict__ Wswz, const float* __restrict__ Wv2,
    const float* __restrict__ bv2, const float* __restrict__ Ycn,
    float* __restrict__ q1, float* __restrict__ qtot)
{
    const int p   = blockIdx.x;          // mask pair: masks p, p+16
    const int btg = blockIdx.y;          // bt group of 4
    const int t = threadIdx.x;
    const int w = t >> 6, lane = t & 63;
    const int bt = btg * 4 + w;
    const int quad = lane >> 4, l16 = lane & 15;
    const int im[2] = { p, p + 16 };
    const bool dotot = (p == (btg & 15));

    __shared__ unsigned short Wl[2][2][4][2][512];  // [buf][mask][nf][half][512] = 32 KB
    __shared__ float qs_s[4][16][33];               // per-wave qs tile

    // qs into LDS (per wave)
    {
        int b = lane >> 2, a0 = (lane & 3) * 8;
        const float* src = qs + (size_t)(bt * 16 + b) * NA + a0;
        #pragma unroll
        for (int u = 0; u < 8; u++) qs_s[w][b][a0 + u] = src[u];
    }

    // A fragments (agent-i k-chunk of st) for both masks
    bf16x8 A0[2], A1[2];
    #pragma unroll
    for (int m = 0; m < 2; m++) {
        A0[m] = *(const bf16x8*)(stA + ((size_t)bt * 64 + 2 * im[m] + 0) * 512 + lane * 8);
        A1[m] = *(const bf16x8*)(stA + ((size_t)bt * 64 + 2 * im[m] + 1) * 512 + lane * 8);
    }

    const float* Yb = Ycn + (size_t)bt * NFRG * 256 + lane * 4;

    // stage frag-group fg (frags fg*4..fg*4+3, both masks) into buffer buf.
    auto stage = [&](int fg, int buf) {
        #pragma unroll
        for (int j = 0; j < 4; j++) {
            const int c  = w * 4 + j;          // 0..15
            const int m  = c >> 3;
            const int nf = (c >> 1) & 3;
            const int h  = c & 1;
            const unsigned short* g = Wswz
                + ((size_t)(im[m] * NFRG + fg * 4 + nf) * 2 + h) * 512 + lane * 8;
            stage16(g, &Wl[buf][m][nf][h][0]);
        }
    };

    floatx4 yv[4], yn[4], acc[2][4];

    auto wmfma = [&](int buf) {
        #pragma unroll
        for (int m = 0; m < 2; m++)
            #pragma unroll
            for (int nf = 0; nf < 4; nf++) {
                bf16x8 w0 = *(const bf16x8*)&Wl[buf][m][nf][0][lane * 8];
                bf16x8 w1 = *(const bf16x8*)&Wl[buf][m][nf][1][lane * 8];
                floatx4 a = __builtin_amdgcn_mfma_f32_16x16x32_bf16(A0[m], w0, yv[nf], 0, 0, 0);
                acc[m][nf] = __builtin_amdgcn_mfma_f32_16x16x32_bf16(A1[m], w1, a, 0, 0, 0);
            }
    };

    floatx4 hid[2][4];
    #pragma unroll
    for (int m = 0; m < 2; m++)
        #pragma unroll
        for (int nf = 0; nf < 4; nf++) hid[m][nf] = (floatx4)0.f;

    floatx4 hidT[4], wffT[4], b1fT[4], vaccT = (floatx4)0.f;
    #pragma unroll
    for (int nf = 0; nf < 4; nf++) hidT[nf] = (floatx4)0.f;

    // prologue: stage group 0, prefetch Ycn group 0
    stage(0, 0);
    #pragma unroll
    for (int nf = 0; nf < 4; nf++) yv[nf] = *(const floatx4*)(Yb + (size_t)nf * 256);
    __syncthreads();

    // main agent loop: groups 0..31 (agents)
    for (int fg = 0; fg < 32; fg++) {
        const int cur = fg & 1;
        stage(fg + 1, cur ^ 1);
        {
            const float* yp = Yb + (size_t)(fg + 1) * 4 * 256;
            #pragma unroll
            for (int nf = 0; nf < 4; nf++) yn[nf] = *(const floatx4*)(yp + (size_t)nf * 256);
        }
        wmfma(cur);
        float qv[4];
        #pragma unroll
        for (int r = 0; r < 4; r++) qv[r] = qs_s[w][quad * 4 + r][fg];
        #pragma unroll
        for (int m = 0; m < 2; m++)
            #pragma unroll
            for (int nf = 0; nf < 4; nf++)
                #pragma unroll
                for (int r = 0; r < 4; r++)
                    hid[m][nf][r] += qv[r] * fabsf(acc[m][nf][r]);
        if (dotot) {
            #pragma unroll
            for (int nf = 0; nf < 4; nf++)
                #pragma unroll
                for (int r = 0; r < 4; r++)
                    hidT[nf][r] += qv[r] * fabsf(yv[nf][r]);
        }
        #pragma unroll
        for (int nf = 0; nf < 4; nf++) yv[nf] = yn[nf];
        __syncthreads();
    }

    floatx4 wff[2][4], b1f[2][4], vacc[2];

    // group 32: wf frags (128..131)   [uses buf 0; fg=31 staged into buf 0]
    {
        stage(33, 1);
        {
            const float* yp = Yb + (size_t)33 * 4 * 256;
            #pragma unroll
            for (int nf = 0; nf < 4; nf++) yn[nf] = *(const floatx4*)(yp + (size_t)nf * 256);
        }
        wmfma(0);
        #pragma unroll
        for (int m = 0; m < 2; m++)
            #pragma unroll
            for (int nf = 0; nf < 4; nf++)
                #pragma unroll
                for (int r = 0; r < 4; r++) wff[m][nf][r] = fabsf(acc[m][nf][r]);
        if (dotot) {
            #pragma unroll
            for (int nf = 0; nf < 4; nf++)
                #pragma unroll
                for (int r = 0; r < 4; r++) wffT[nf][r] = fabsf(yv[nf][r]);
        }
        #pragma unroll
        for (int nf = 0; nf < 4; nf++) yv[nf] = yn[nf];
        __syncthreads();
    }
    // group 33: b1 frags (132..135)
    {
        stage(34, 0);
        {
            const float* yp = Yb + (size_t)34 * 4 * 256;
            #pragma unroll
            for (int nf = 0; nf < 4; nf++) yn[nf] = *(const floatx4*)(yp + (size_t)nf * 256);
        }
        wmfma(1);
        #pragma unroll
        for (int m = 0; m < 2; m++)
            #pragma unroll
            for (int nf = 0; nf < 4; nf++)
                #pragma unroll
                for (int r = 0; r < 4; r++) b1f[m][nf][r] = -acc[m][nf][r];
        if (dotot) {
            #pragma unroll
            for (int nf = 0; nf < 4; nf++)
                #pragma unroll
                for (int r = 0; r < 4; r++) b1fT[nf][r] = -yv[nf][r];
        }
        #pragma unroll
        for (int nf = 0; nf < 4; nf++) yv[nf] = yn[nf];
        __syncthreads();
    }
    // group 34: v frags (136..139)
    {
        wmfma(0);
        float wv2f[4];
        #pragma unroll
        for (int nf = 0; nf < 4; nf++) wv2f[nf] = Wv2[nf * 16 + l16];
        #pragma unroll
        for (int m = 0; m < 2; m++) {
            vacc[m] = (floatx4)0.f;
            #pragma unroll
            for (int nf = 0; nf < 4; nf++)
                #pragma unroll
                for (int r = 0; r < 4; r++)
                    vacc[m][r] += fmaxf(-acc[m][nf][r], 0.f) * wv2f[nf];
        }
        if (dotot) {
            #pragma unroll
            for (int nf = 0; nf < 4; nf++)
                #pragma unroll
                for (int r = 0; r < 4; r++)
                    vaccT[r] += fmaxf(-yv[nf][r], 0.f) * wv2f[nf];
        }
    }

    const float bv2v = bv2[0];
    #pragma unroll
    for (int m = 0; m < 2; m++)
        #pragma unroll
        for (int r = 0; r < 4; r++) {
            float s = vacc[m][r];
            #pragma unroll
            for (int nf = 0; nf < 4; nf++) {
                float h = hid[m][nf][r] + b1f[m][nf][r];
                h = h > 0.f ? h : expm1f(h);
                s += h * wff[m][nf][r];
            }
            s += __shfl_xor(s, 1); s += __shfl_xor(s, 2);
            s += __shfl_xor(s, 4); s += __shfl_xor(s, 8);
            if (l16 == 0) q1[(size_t)im[m] * BT + bt * 16 + quad * 4 + r] = s + bv2v;
        }

    if (dotot) {
        #pragma unroll
        for (int r = 0; r < 4; r++) {
            float s = vaccT[r];
            #pragma unroll
            for (int nf = 0; nf < 4; nf++) {
                float h = hidT[nf][r] + b1fT[nf][r];
                h = h > 0.f ? h : expm1f(h);
                s += h * wffT[nf][r];
            }
            s += __shfl_xor(s, 1); s += __shfl_xor(s, 2);
            s += __shfl_xor(s, 4); s += __shfl_xor(s, 8);
            if (l16 == 0) qtot[bt * 16 + quad * 4 + r] = s + bv2v;
        }
    }
}

// ---------------- K4: wc + final mix (q_tot precomputed by k3) -----------
// R7: pass-1 (full Ycn sweep + reduction, existed only to produce q_tot)
// removed; qt is loaded from qtot[]. Remaining: tail frags, wc, pass 2.
__global__ __launch_bounds__(256) void k4_final(
    const float* __restrict__ qs, const float* __restrict__ Ycn,
    const float* __restrict__ q1, const float* __restrict__ qtot,
    const float* __restrict__ Wv2, const float* __restrict__ bv2,
    float* __restrict__ out)
{
    const int bt = blockIdx.x;
    __shared__ float qs_s[16][33];
    __shared__ float qw_s[16][33];
    __shared__ float hidp[4][16][64];
    __shared__ float wfb[16][64], b1b[16][64], vb[16][64];
    __shared__ float qt[16];

    const int t = threadIdx.x, w = t >> 6, lane = t & 63;
    const int quad = lane >> 4, l16 = lane & 15;
    const float bv2v = bv2[0];

    {
        int l = t * 2;
        float2 v = *(const float2*)&qs[(size_t)(bt * 16 + (l >> 5)) * NA + (l & 31)];
        qs_s[l >> 5][(l & 31) + 0] = v.x;
        qs_s[l >> 5][(l & 31) + 1] = v.y;
    }
    if (t < 16) qt[t] = qtot[bt * 16 + t];

    const float* Yb = Ycn + (size_t)bt * NFRG * 256;

    // tail frags: 3 per wave -> wfb / b1b / vb
    #pragma unroll
    for (int fi = 0; fi < 3; fi++) {
        const int nft = w * 3 + fi;
        floatx4 c = *(const floatx4*)(Yb + (size_t)(128 + nft) * 256 + lane * 4);
        const int e = (nft & 3) * 16 + l16;
        #pragma unroll
        for (int r = 0; r < 4; r++) {
            int b = quad * 4 + r;
            if (nft < 4)      wfb[b][e] = fabsf(c[r]);
            else if (nft < 8) b1b[b][e] = -c[r];
            else              vb[b][e]  = fmaxf(-c[r], 0.f) * Wv2[e];
        }
    }
    __syncthreads();

    // wc: thread (w,quad,l16) -> row rr = w*4+quad, agents 2*l16, 2*l16+1
    {
        const int rr = w * 4 + quad;
        float qtv = qt[rr];
        float d0 = fabsf(qtv - q1[(size_t)(2 * l16 + 0) * BT + bt * 16 + rr]);
        float d1 = fabsf(qtv - q1[(size_t)(2 * l16 + 1) * BT + bt * 16 + rr]);
        float ss = d0 * d0 + d1 * d1;
        ss += __shfl_xor(ss, 1); ss += __shfl_xor(ss, 2);
        ss += __shfl_xor(ss, 4); ss += __shfl_xor(ss, 8);
        float inv = 1.f / fmaxf(sqrtf(ss), 1e-12f);
        qw_s[rr][2 * l16 + 0] = qs_s[rr][2 * l16 + 0] * d0 * inv;
        qw_s[rr][2 * l16 + 1] = qs_s[rr][2 * l16 + 1] * d1 * inv;
    }
    __syncthreads();

    // pass 2: hid with qs*wc
    floatx4 hid2[4];
    #pragma unroll
    for (int nf = 0; nf < 4; nf++) hid2[nf] = (floatx4)0.f;
    for (int ia = 0; ia < 8; ia++) {
        const int a = w * 8 + ia;
        const float* yp = Yb + (size_t)(a * 4) * 256 + lane * 4;
        float qv[4];
        #pragma unroll
        for (int r = 0; r < 4; r++) qv[r] = qw_s[quad * 4 + r][a];
        #pragma unroll
        for (int nf = 0; nf < 4; nf++) {
            floatx4 c = *(const floatx4*)(yp + nf * 256);
            #pragma unroll
            for (int r = 0; r < 4; r++) hid2[nf][r] += qv[r] * fabsf(c[r]);
        }
    }
    #pragma unroll
    for (int nf = 0; nf < 4; nf++)
        #pragma unroll
        for (int r = 0; r < 4; r++)
            hidp[w][quad * 4 + r][nf * 16 + l16] = hid2[nf][r];
    __syncthreads();

    #pragma unroll
    for (int bb = 0; bb < 4; bb++) {
        int b = w * 4 + bb;
        float h = hidp[0][b][lane] + hidp[1][b][lane]
                + hidp[2][b][lane] + hidp[3][b][lane] + b1b[b][lane];
        h = h > 0.f ? h : expm1f(h);
        float val = h * wfb[b][lane] + vb[b][lane];
        #pragma unroll
        for (int off = 32; off > 0; off >>= 1) val += __shfl_xor(val, off);
        if (lane == 0) out[bt * 16 + b] = val + bv2v;
    }
}

extern "C" void kernel_launch(void* const* d_in, const int* in_sizes, int n_in,
                              void* d_out, int out_size, void* d_ws, size_t ws_size,
                              hipStream_t stream) {
    const float* qs  = (const float*)d_in[0];
    const float* st  = (const float*)d_in[1];
    const float* Ww1 = (const float*)d_in[2];
    const float* bw1 = (const float*)d_in[3];
    const float* Wwf = (const float*)d_in[4];
    const float* bwf = (const float*)d_in[5];
    const float* Wb1 = (const float*)d_in[6];
    const float* bb1 = (const float*)d_in[7];
    const float* Wv1 = (const float*)d_in[8];
    const float* bv1 = (const float*)d_in[9];
    const float* Wv2 = (const float*)d_in[10];
    const float* bv2 = (const float*)d_in[11];
    float* out = (float*)d_out;

    // workspace (~37 MB, same footprint as proven layout; old bcat slot
    // (2304 f32) reused as qtot (2048 f32) — no footprint change)
    float* Ycn           = (float*)d_ws;                           // 128*144*256 f32 = 18.87 MB
    unsigned short* stA  = (unsigned short*)(Ycn + (size_t)128 * NFRG * 256); // 8.39 MB
    unsigned short* Wswz = stA + (size_t)SD * SD;                  // 32*144*1024 bf16 = 9.44 MB
    float* qtot          = (float*)(Wswz + (size_t)32 * NFRG * 1024); // 2048 f32 (ex-bcat slot)
    float* q1v           = qtot + NFRG * 16;                       // 32*2048 f32

    k0_prep<<<4352, 256, 0, stream>>>(st, stA, Ww1, Wwf, Wb1, Wv1, Wswz);

    k1_gemm<<<dim3(BT / 128, NFRG / 8), 512, 0, stream>>>(stA, Wswz, bw1, bwf, bb1, bv1, Ycn);
    k3_q1  <<<dim3(16, 32), 256, 0, stream>>>(stA, qs, Wswz, Wv2, bv2, Ycn, q1v, qtot);
    k4_final<<<BT / 16, 256, 0, stream>>>(qs, Ycn, q1v, qtot, Wv2, bv2, out);
}

// Round 12
// 180.725 us; speedup vs baseline: 1.0241x; 1.0209x over previous
//
#include <hip/hip_runtime.h>
#include <math.h>
#include <stdint.h>

#define NA 32          // N_AGENTS
#define SD 2048        // STATE_DIM
#define BT 2048        // B = BS*T
#define NFRG 144       // col frags (2304 padded cols / 16); 128 agent + 12 tail + 4 pad

typedef float floatx4 __attribute__((ext_vector_type(4)));
typedef short bf16x8  __attribute__((ext_vector_type(8)));

__device__ __forceinline__ unsigned short f2bf(float f) {
    union { float f; uint32_t u; } v; v.f = f;
    uint32_t r = v.u + 0x7FFFu + ((v.u >> 16) & 1u);
    return (unsigned short)(r >> 16);
}

__device__ __forceinline__ void stage16(const void* g, void* l) {
    __builtin_amdgcn_global_load_lds(
        (const __attribute__((address_space(1))) void*)g,
        (__attribute__((address_space(3))) void*)l,
        16, 0, 0);
}

// ---- fragment layouts ----
// A-frag (stA):  elem((bt*64+kc)*512 + (quad*16+l16)*8 + j) = st[bt*16+l16][kc*32+quad*8+j]
// B-frag (Wswz): elem(((i*NFRG+f)*2+h)*512 + (quad*16+l16)*8 + j) = W[n=f*16+l16][k=i*64+h*32+quad*8+j]
// C-frag (Ycn, f32): elem((bt*NFRG+f)*256 + (quad*16+l16)*4 + r) = -Y[bt*16+quad*4+r][f*16+l16]

// ---------------- K0: fused input transforms (ast + wswz) ----------------
// blocks 0..2047: st -> A-frag bf16.  blocks 2048..4351: weights -> B-frag.
__global__ __launch_bounds__(256) void k0_prep(const float* __restrict__ st,
                                               unsigned short* __restrict__ stA,
                                               const float* __restrict__ Ww1,
                                               const float* __restrict__ Wwf,
                                               const float* __restrict__ Wb1,
                                               const float* __restrict__ Wv1,
                                               unsigned short* __restrict__ Wswz) {
    const int blk = blockIdx.x;
    const int t = threadIdx.x;
    const int l = t & 63;
    const int quad = l >> 4, l16 = l & 15;

    if (blk < 2048) {               // ---- ast part: grid (16,128) flattened
        const int bx = blk & 15, bt = blk >> 4;
        const int kc = bx * 4 + (t >> 6);   // 0..63
        const float* src = st + (size_t)(bt * 16 + l16) * SD + kc * 32 + quad * 8;
        float4 v0 = *(const float4*)(src);
        float4 v1 = *(const float4*)(src + 4);
        ushort4 o0, o1;
        o0.x = f2bf(v0.x); o0.y = f2bf(v0.y); o0.z = f2bf(v0.z); o0.w = f2bf(v0.w);
        o1.x = f2bf(v1.x); o1.y = f2bf(v1.y); o1.z = f2bf(v1.z); o1.w = f2bf(v1.w);
        unsigned short* dst = stA + ((size_t)bt * 64 + kc) * 512 + l * 8;
        *(ushort4*)(dst)     = o0;
        *(ushort4*)(dst + 4) = o1;
    } else {                        // ---- wswz part: grid (72,32) flattened
        const int b2 = blk - 2048;
        const int bx = b2 % 72, i = b2 / 72;        // i = k-chunk 0..31
        const int f = bx * 2 + (t >> 7);            // frag 0..143
        const int h = (t >> 6) & 1;
        const int n = f * 16 + l16;

        const float* src; int ld, nr = 0;
        if (f < 128)      { src = Ww1; ld = 2048; nr = n; }
        else if (f < 132) { src = Wwf; ld = 64;   nr = n - 2048; }
        else if (f < 136) { src = Wb1; ld = 64;   nr = n - 2112; }
        else if (f < 140) { src = Wv1; ld = 64;   nr = n - 2176; }
        else              { src = nullptr; ld = 64; }

        const int k0 = i * 64 + h * 32 + quad * 8;
        unsigned short vals[8];
        #pragma unroll
        for (int j = 0; j < 8; j++)
            vals[j] = src ? f2bf(src[(size_t)(k0 + j) * ld + nr]) : (unsigned short)0;

        unsigned short* dst = Wswz + (((size_t)i * NFRG + f) * 2 + h) * 512 + l * 8;
        ushort4 o0 = {vals[0], vals[1], vals[2], vals[3]};
        ushort4 o1 = {vals[4], vals[5], vals[6], vals[7]};
        *(ushort4*)(dst)     = o0;
        *(ushort4*)(dst + 4) = o1;
    }
}

// ---------------- K1: Ycn = -(st @ Wcat + bias), LDS-staged tiles --------
// R5-proven 64x128 / 256-thread form. R6 (reg-stream A) and R10 (128x128
// 512-thread) BOTH regressed — R10 even poisoned the downstream k3 by
// ~23 us (cache/power state coupling). Do not change this kernel's shape.
__global__ __launch_bounds__(256) void k1_gemm(const unsigned short* __restrict__ stA,
                                               const unsigned short* __restrict__ Wswz,
                                               const float* __restrict__ bw1,
                                               const float* __restrict__ bwf,
                                               const float* __restrict__ bb1,
                                               const float* __restrict__ bv1,
                                               float* __restrict__ Ycn)
{
    const int t = threadIdx.x;
    const int m0t = blockIdx.x * 4;   // btile base (64 rows)
    const int n0f = blockIdx.y * 8;   // frag base (128 cols)
    const int wid = t >> 6, lane = t & 63;
    const int wm = wid & 1, wn = wid >> 1;
    const int l16 = lane & 15;

    __shared__ unsigned short As[2][2][4][512];   // [buf][kk][btile][512] = 16 KB
    __shared__ unsigned short Bs[2][2][8][512];   // [buf][kk][frag ][512] = 32 KB

    floatx4 acc[2][4];
    #pragma unroll
    for (int i = 0; i < 2; i++)
        #pragma unroll
        for (int j = 0; j < 4; j++) acc[i][j] = (floatx4)0.f;

    // stage iteration 'it' (kc = it*2, it*2+1) into buffer buf.
    // 24 chunks of 1 KB; this wave issues chunks c = wid*6 .. wid*6+5.
    auto stage = [&](int it, int buf) {
        #pragma unroll
        for (int j = 0; j < 6; j++) {
            const int c   = wid * 6 + j;        // 0..23
            const int kk  = c / 12;             // 0..1
            const int rem = c % 12;
            if (rem < 4) {
                const unsigned short* gp = stA
                    + ((size_t)(m0t + rem) * 64 + (it * 2 + kk)) * 512 + lane * 8;
                stage16(gp, &As[buf][kk][rem][0]);
            } else {
                const int f = rem - 4;          // 0..7
                const unsigned short* gp = Wswz
                    + (((size_t)it * NFRG + (n0f + f)) * 2 + kk) * 512 + lane * 8;
                stage16(gp, &Bs[buf][kk][f][0]);
            }
        }
    };

    stage(0, 0);
    __syncthreads();

    for (int it = 0; it < 32; it++) {
        const int buf = it & 1;
        if (it < 31) stage(it + 1, buf ^ 1);
        #pragma unroll
        for (int kk = 0; kk < 2; kk++) {
            bf16x8 a0 = *(const bf16x8*)&As[buf][kk][wm * 2 + 0][lane * 8];
            bf16x8 a1 = *(const bf16x8*)&As[buf][kk][wm * 2 + 1][lane * 8];
            bf16x8 b[4];
            #pragma unroll
            for (int nf = 0; nf < 4; nf++)
                b[nf] = *(const bf16x8*)&Bs[buf][kk][wn * 4 + nf][lane * 8];
            #pragma unroll
            for (int nf = 0; nf < 4; nf++) {
                acc[0][nf] = __builtin_amdgcn_mfma_f32_16x16x32_bf16(a0, b[nf], acc[0][nf], 0, 0, 0);
                acc[1][nf] = __builtin_amdgcn_mfma_f32_16x16x32_bf16(a1, b[nf], acc[1][nf], 0, 0, 0);
            }
        }
        __syncthreads();
    }

    #pragma unroll
    for (int mf = 0; mf < 2; mf++)
        #pragma unroll
        for (int nf = 0; nf < 4; nf++) {
            const int f  = n0f + wn * 4 + nf;
            const int bt = m0t + wm * 2 + mf;
            const int n  = f * 16 + l16;
            float bias;
            if (f < 128)      bias = bw1[n];
            else if (f < 132) bias = bwf[n - 2048];
            else if (f < 136) bias = bb1[n - 2112];
            else if (f < 140) bias = bv1[n - 2176];
            else              bias = 0.f;
            floatx4 o;
            #pragma unroll
            for (int r = 0; r < 4; r++) o[r] = -(acc[mf][nf][r] + bias);
            *(floatx4*)(Ycn + ((size_t)bt * NFRG + f) * 256 + lane * 4) = o;
        }
}

// ---------------- K3: q1[i][b] (+ q_tot on elected block), staged W ------
// R8-proven version (best total 180.0): mask-PAIR per block, 512 blocks,
// stage -> compute -> __syncthreads. Ledger: do NOT re-pipeline (R2-R4),
// do NOT split the pair (R9). Floor ~47-49 us in this decomposition.
// dotot election p == (btg & 15): bijective, XCD-spread (4 per XCD).
__global__ __launch_bounds__(256) void k3_q1(
    const unsigned short* __restrict__ stA, const float* __restrict__ qs,
    const unsigned short* __restrict__ Wswz, const float* __restrict__ Wv2,
    const float* __restrict__ bv2, const float* __restrict__ Ycn,
    float* __restrict__ q1, float* __restrict__ qtot)
{
    const int p   = blockIdx.x;          // mask pair: masks p, p+16
    const int btg = blockIdx.y;          // bt group of 4
    const int t = threadIdx.x;
    const int w = t >> 6, lane = t & 63;
    const int bt = btg * 4 + w;
    const int quad = lane >> 4, l16 = lane & 15;
    const int im[2] = { p, p + 16 };
    const bool dotot = (p == (btg & 15));

    __shared__ unsigned short Wl[2][2][4][2][512];  // [buf][mask][nf][half][512] = 32 KB
    __shared__ float qs_s[4][16][33];               // per-wave qs tile

    // qs into LDS (per wave)
    {
        int b = lane >> 2, a0 = (lane & 3) * 8;
        const float* src = qs + (size_t)(bt * 16 + b) * NA + a0;
        #pragma unroll
        for (int u = 0; u < 8; u++) qs_s[w][b][a0 + u] = src[u];
    }

    // A fragments (agent-i k-chunk of st) for both masks
    bf16x8 A0[2], A1[2];
    #pragma unroll
    for (int m = 0; m < 2; m++) {
        A0[m] = *(const bf16x8*)(stA + ((size_t)bt * 64 + 2 * im[m] + 0) * 512 + lane * 8);
        A1[m] = *(const bf16x8*)(stA + ((size_t)bt * 64 + 2 * im[m] + 1) * 512 + lane * 8);
    }

    const float* Yb = Ycn + (size_t)bt * NFRG * 256 + lane * 4;

    // stage frag-group fg (frags fg*4..fg*4+3, both masks) into buffer buf.
    auto stage = [&](int fg, int buf) {
        #pragma unroll
        for (int j = 0; j < 4; j++) {
            const int c  = w * 4 + j;          // 0..15
            const int m  = c >> 3;
            const int nf = (c >> 1) & 3;
            const int h  = c & 1;
            const unsigned short* g = Wswz
                + ((size_t)(im[m] * NFRG + fg * 4 + nf) * 2 + h) * 512 + lane * 8;
            stage16(g, &Wl[buf][m][nf][h][0]);
        }
    };

    floatx4 yv[4], yn[4], acc[2][4];

    auto wmfma = [&](int buf) {
        #pragma unroll
        for (int m = 0; m < 2; m++)
            #pragma unroll
            for (int nf = 0; nf < 4; nf++) {
                bf16x8 w0 = *(const bf16x8*)&Wl[buf][m][nf][0][lane * 8];
                bf16x8 w1 = *(const bf16x8*)&Wl[buf][m][nf][1][lane * 8];
                floatx4 a = __builtin_amdgcn_mfma_f32_16x16x32_bf16(A0[m], w0, yv[nf], 0, 0, 0);
                acc[m][nf] = __builtin_amdgcn_mfma_f32_16x16x32_bf16(A1[m], w1, a, 0, 0, 0);
            }
    };

    floatx4 hid[2][4];
    #pragma unroll
    for (int m = 0; m < 2; m++)
        #pragma unroll
        for (int nf = 0; nf < 4; nf++) hid[m][nf] = (floatx4)0.f;

    floatx4 hidT[4], wffT[4], b1fT[4], vaccT = (floatx4)0.f;
    #pragma unroll
    for (int nf = 0; nf < 4; nf++) hidT[nf] = (floatx4)0.f;

    // prologue: stage group 0, prefetch Ycn group 0
    stage(0, 0);
    #pragma unroll
    for (int nf = 0; nf < 4; nf++) yv[nf] = *(const floatx4*)(Yb + (size_t)nf * 256);
    __syncthreads();

    // main agent loop: groups 0..31 (agents)
    for (int fg = 0; fg < 32; fg++) {
        const int cur = fg & 1;
        stage(fg + 1, cur ^ 1);
        {
            const float* yp = Yb + (size_t)(fg + 1) * 4 * 256;
            #pragma unroll
            for (int nf = 0; nf < 4; nf++) yn[nf] = *(const floatx4*)(yp + (size_t)nf * 256);
        }
        wmfma(cur);
        float qv[4];
        #pragma unroll
        for (int r = 0; r < 4; r++) qv[r] = qs_s[w][quad * 4 + r][fg];
        #pragma unroll
        for (int m = 0; m < 2; m++)
            #pragma unroll
            for (int nf = 0; nf < 4; nf++)
                #pragma unroll
                for (int r = 0; r < 4; r++)
                    hid[m][nf][r] += qv[r] * fabsf(acc[m][nf][r]);
        if (dotot) {
            #pragma unroll
            for (int nf = 0; nf < 4; nf++)
                #pragma unroll
                for (int r = 0; r < 4; r++)
                    hidT[nf][r] += qv[r] * fabsf(yv[nf][r]);
        }
        #pragma unroll
        for (int nf = 0; nf < 4; nf++) yv[nf] = yn[nf];
        __syncthreads();
    }

    floatx4 wff[2][4], b1f[2][4], vacc[2];

    // group 32: wf frags (128..131)   [uses buf 0; fg=31 staged into buf 0]
    {
        stage(33, 1);
        {
            const float* yp = Yb + (size_t)33 * 4 * 256;
            #pragma unroll
            for (int nf = 0; nf < 4; nf++) yn[nf] = *(const floatx4*)(yp + (size_t)nf * 256);
        }
        wmfma(0);
        #pragma unroll
        for (int m = 0; m < 2; m++)
            #pragma unroll
            for (int nf = 0; nf < 4; nf++)
                #pragma unroll
                for (int r = 0; r < 4; r++) wff[m][nf][r] = fabsf(acc[m][nf][r]);
        if (dotot) {
            #pragma unroll
            for (int nf = 0; nf < 4; nf++)
                #pragma unroll
                for (int r = 0; r < 4; r++) wffT[nf][r] = fabsf(yv[nf][r]);
        }
        #pragma unroll
        for (int nf = 0; nf < 4; nf++) yv[nf] = yn[nf];
        __syncthreads();
    }
    // group 33: b1 frags (132..135)
    {
        stage(34, 0);
        {
            const float* yp = Yb + (size_t)34 * 4 * 256;
            #pragma unroll
            for (int nf = 0; nf < 4; nf++) yn[nf] = *(const floatx4*)(yp + (size_t)nf * 256);
        }
        wmfma(1);
        #pragma unroll
        for (int m = 0; m < 2; m++)
            #pragma unroll
            for (int nf = 0; nf < 4; nf++)
                #pragma unroll
                for (int r = 0; r < 4; r++) b1f[m][nf][r] = -acc[m][nf][r];
        if (dotot) {
            #pragma unroll
            for (int nf = 0; nf < 4; nf++)
                #pragma unroll
                for (int r = 0; r < 4; r++) b1fT[nf][r] = -yv[nf][r];
        }
        #pragma unroll
        for (int nf = 0; nf < 4; nf++) yv[nf] = yn[nf];
        __syncthreads();
    }
    // group 34: v frags (136..139)
    {
        wmfma(0);
        float wv2f[4];
        #pragma unroll
        for (int nf = 0; nf < 4; nf++) wv2f[nf] = Wv2[nf * 16 + l16];
        #pragma unroll
        for (int m = 0; m < 2; m++) {
            vacc[m] = (floatx4)0.f;
            #pragma unroll
            for (int nf = 0; nf < 4; nf++)
                #pragma unroll
                for (int r = 0; r < 4; r++)
                    vacc[m][r] += fmaxf(-acc[m][nf][r], 0.f) * wv2f[nf];
        }
        if (dotot) {
            #pragma unroll
            for (int nf = 0; nf < 4; nf++)
                #pragma unroll
                for (int r = 0; r < 4; r++)
                    vaccT[r] += fmaxf(-yv[nf][r], 0.f) * wv2f[nf];
        }
    }

    const float bv2v = bv2[0];
    #pragma unroll
    for (int m = 0; m < 2; m++)
        #pragma unroll
        for (int r = 0; r < 4; r++) {
            float s = vacc[m][r];
            #pragma unroll
            for (int nf = 0; nf < 4; nf++) {
                float h = hid[m][nf][r] + b1f[m][nf][r];
                h = h > 0.f ? h : expm1f(h);
                s += h * wff[m][nf][r];
            }
            s += __shfl_xor(s, 1); s += __shfl_xor(s, 2);
            s += __shfl_xor(s, 4); s += __shfl_xor(s, 8);
            if (l16 == 0) q1[(size_t)im[m] * BT + bt * 16 + quad * 4 + r] = s + bv2v;
        }

    if (dotot) {
        #pragma unroll
        for (int r = 0; r < 4; r++) {
            float s = vaccT[r];
            #pragma unroll
            for (int nf = 0; nf < 4; nf++) {
                float h = hidT[nf][r] + b1fT[nf][r];
                h = h > 0.f ? h : expm1f(h);
                s += h * wffT[nf][r];
            }
            s += __shfl_xor(s, 1); s += __shfl_xor(s, 2);
            s += __shfl_xor(s, 4); s += __shfl_xor(s, 8);
            if (l16 == 0) qtot[bt * 16 + quad * 4 + r] = s + bv2v;
        }
    }
}

// ---------------- K4: wc + final mix (q_tot precomputed by k3) -----------
// R11: XCD affinity remap. k1 (64x128, grid 32x18) writes Ycn btile g on
// XCD g%8... precisely: writer block bx = g/4... bx covers btiles 4bx..
// 4bx+3, XCD = bx%8 = (bt>>2)%8. Remap k4's block->bt so reader XCD
// (blk%8) == (bt>>2)%8: bt = 4*(blk&7) + 32*((blk>>3)&3) + (blk>>5)
// (bijective over 0..127). Ycn (and qtot, writer XCD (bt/4)%8) reads
// become local-L2 hits instead of 7/8 cross-XCD L3 trips.
__global__ __launch_bounds__(256) void k4_final(
    const float* __restrict__ qs, const float* __restrict__ Ycn,
    const float* __restrict__ q1, const float* __restrict__ qtot,
    const float* __restrict__ Wv2, const float* __restrict__ bv2,
    float* __restrict__ out)
{
    const int blk = blockIdx.x;
    const int bt = 4 * (blk & 7) + 32 * ((blk >> 3) & 3) + (blk >> 5);
    __shared__ float qs_s[16][33];
    __shared__ float qw_s[16][33];
    __shared__ float hidp[4][16][64];
    __shared__ float wfb[16][64], b1b[16][64], vb[16][64];
    __shared__ float qt[16];

    const int t = threadIdx.x, w = t >> 6, lane = t & 63;
    const int quad = lane >> 4, l16 = lane & 15;
    const float bv2v = bv2[0];

    {
        int l = t * 2;
        float2 v = *(const float2*)&qs[(size_t)(bt * 16 + (l >> 5)) * NA + (l & 31)];
        qs_s[l >> 5][(l & 31) + 0] = v.x;
        qs_s[l >> 5][(l & 31) + 1] = v.y;
    }
    if (t < 16) qt[t] = qtot[bt * 16 + t];

    const float* Yb = Ycn + (size_t)bt * NFRG * 256;

    // tail frags: 3 per wave -> wfb / b1b / vb
    #pragma unroll
    for (int fi = 0; fi < 3; fi++) {
        const int nft = w * 3 + fi;
        floatx4 c = *(const floatx4*)(Yb + (size_t)(128 + nft) * 256 + lane * 4);
        const int e = (nft & 3) * 16 + l16;
        #pragma unroll
        for (int r = 0; r < 4; r++) {
            int b = quad * 4 + r;
            if (nft < 4)      wfb[b][e] = fabsf(c[r]);
            else if (nft < 8) b1b[b][e] = -c[r];
            else              vb[b][e]  = fmaxf(-c[r], 0.f) * Wv2[e];
        }
    }
    __syncthreads();

    // wc: thread (w,quad,l16) -> row rr = w*4+quad, agents 2*l16, 2*l16+1
    {
        const int rr = w * 4 + quad;
        float qtv = qt[rr];
        float d0 = fabsf(qtv - q1[(size_t)(2 * l16 + 0) * BT + bt * 16 + rr]);
        float d1 = fabsf(qtv - q1[(size_t)(2 * l16 + 1) * BT + bt * 16 + rr]);
        float ss = d0 * d0 + d1 * d1;
        ss += __shfl_xor(ss, 1); ss += __shfl_xor(ss, 2);
        ss += __shfl_xor(ss, 4); ss += __shfl_xor(ss, 8);
        float inv = 1.f / fmaxf(sqrtf(ss), 1e-12f);
        qw_s[rr][2 * l16 + 0] = qs_s[rr][2 * l16 + 0] * d0 * inv;
        qw_s[rr][2 * l16 + 1] = qs_s[rr][2 * l16 + 1] * d1 * inv;
    }
    __syncthreads();

    // pass 2: hid with qs*wc
    floatx4 hid2[4];
    #pragma unroll
    for (int nf = 0; nf < 4; nf++) hid2[nf] = (floatx4)0.f;
    for (int ia = 0; ia < 8; ia++) {
        const int a = w * 8 + ia;
        const float* yp = Yb + (size_t)(a * 4) * 256 + lane * 4;
        float qv[4];
        #pragma unroll
        for (int r = 0; r < 4; r++) qv[r] = qw_s[quad * 4 + r][a];
        #pragma unroll
        for (int nf = 0; nf < 4; nf++) {
            floatx4 c = *(const floatx4*)(yp + nf * 256);
            #pragma unroll
            for (int r = 0; r < 4; r++) hid2[nf][r] += qv[r] * fabsf(c[r]);
        }
    }
    #pragma unroll
    for (int nf = 0; nf < 4; nf++)
        #pragma unroll
        for (int r = 0; r < 4; r++)
            hidp[w][quad * 4 + r][nf * 16 + l16] = hid2[nf][r];
    __syncthreads();

    #pragma unroll
    for (int bb = 0; bb < 4; bb++) {
        int b = w * 4 + bb;
        float h = hidp[0][b][lane] + hidp[1][b][lane]
                + hidp[2][b][lane] + hidp[3][b][lane] + b1b[b][lane];
        h = h > 0.f ? h : expm1f(h);
        float val = h * wfb[b][lane] + vb[b][lane];
        #pragma unroll
        for (int off = 32; off > 0; off >>= 1) val += __shfl_xor(val, off);
        if (lane == 0) out[bt * 16 + b] = val + bv2v;
    }
}

extern "C" void kernel_launch(void* const* d_in, const int* in_sizes, int n_in,
                              void* d_out, int out_size, void* d_ws, size_t ws_size,
                              hipStream_t stream) {
    const float* qs  = (const float*)d_in[0];
    const float* st  = (const float*)d_in[1];
    const float* Ww1 = (const float*)d_in[2];
    const float* bw1 = (const float*)d_in[3];
    const float* Wwf = (const float*)d_in[4];
    const float* bwf = (const float*)d_in[5];
    const float* Wb1 = (const float*)d_in[6];
    const float* bb1 = (const float*)d_in[7];
    const float* Wv1 = (const float*)d_in[8];
    const float* bv1 = (const float*)d_in[9];
    const float* Wv2 = (const float*)d_in[10];
    const float* bv2 = (const float*)d_in[11];
    float* out = (float*)d_out;

    // workspace (~37 MB, same footprint as proven layout; old bcat slot
    // (2304 f32) reused as qtot (2048 f32) — no footprint change)
    float* Ycn           = (float*)d_ws;                           // 128*144*256 f32 = 18.87 MB
    unsigned short* stA  = (unsigned short*)(Ycn + (size_t)128 * NFRG * 256); // 8.39 MB
    unsigned short* Wswz = stA + (size_t)SD * SD;                  // 32*144*1024 bf16 = 9.44 MB
    float* qtot          = (float*)(Wswz + (size_t)32 * NFRG * 1024); // 2048 f32 (ex-bcat slot)
    float* q1v           = qtot + NFRG * 16;                       // 32*2048 f32

    k0_prep<<<4352, 256, 0, stream>>>(st, stA, Ww1, Wwf, Wb1, Wv1, Wswz);

    k1_gemm<<<dim3(BT / 64, NFRG / 8), 256, 0, stream>>>(stA, Wswz, bw1, bwf, bb1, bv1, Ycn);
    k3_q1  <<<dim3(16, 32), 256, 0, stream>>>(stA, qs, Wswz, Wv2, bv2, Ycn, q1v, qtot);
    k4_final<<<BT / 16, 256, 0, stream>>>(qs, Ycn, q1v, qtot, Wv2, bv2, out);
}

// Round 13
// 179.018 us; speedup vs baseline: 1.0339x; 1.0095x over previous
//
#include <hip/hip_runtime.h>
#include <math.h>
#include <stdint.h>

#define NA 32          // N_AGENTS
#define SD 2048        // STATE_DIM
#define BT 2048        // B = BS*T
#define NFRG 144       // col frags (2304 padded cols / 16); 128 agent + 12 tail + 4 pad

typedef float floatx4 __attribute__((ext_vector_type(4)));
typedef short bf16x8  __attribute__((ext_vector_type(8)));

__device__ __forceinline__ unsigned short f2bf(float f) {
    union { float f; uint32_t u; } v; v.f = f;
    uint32_t r = v.u + 0x7FFFu + ((v.u >> 16) & 1u);
    return (unsigned short)(r >> 16);
}

__device__ __forceinline__ void stage16(const void* g, void* l) {
    __builtin_amdgcn_global_load_lds(
        (const __attribute__((address_space(1))) void*)g,
        (__attribute__((address_space(3))) void*)l,
        16, 0, 0);
}

// ---- fragment layouts ----
// A-frag (stA):  elem((bt*64+kc)*512 + (quad*16+l16)*8 + j) = st[bt*16+l16][kc*32+quad*8+j]
// B-frag (Wswz): elem(((i*NFRG+f)*2+h)*512 + (quad*16+l16)*8 + j) = W[n=f*16+l16][k=i*64+h*32+quad*8+j]
// C-frag (Ycn, f32): elem((bt*NFRG+f)*256 + (quad*16+l16)*4 + r) = -Y[bt*16+quad*4+r][f*16+l16]

// ---------------- K0: fused input transforms (ast + wswz + out-init) -----
// blocks 0..2047: st -> A-frag bf16.  blocks 2048..4351: weights -> B-frag.
// block 4352: out[] = bv2 (base value for k4's sliced atomicAdd combine).
__global__ __launch_bounds__(256) void k0_prep(const float* __restrict__ st,
                                               unsigned short* __restrict__ stA,
                                               const float* __restrict__ Ww1,
                                               const float* __restrict__ Wwf,
                                               const float* __restrict__ Wb1,
                                               const float* __restrict__ Wv1,
                                               unsigned short* __restrict__ Wswz,
                                               const float* __restrict__ bv2,
                                               float* __restrict__ out) {
    const int blk = blockIdx.x;
    const int t = threadIdx.x;
    const int l = t & 63;
    const int quad = l >> 4, l16 = l & 15;

    if (blk >= 4352) {              // ---- out-init part
        const float v = bv2[0];
        #pragma unroll
        for (int j = 0; j < 8; j++) out[t * 8 + j] = v;
        return;
    }
    if (blk < 2048) {               // ---- ast part: grid (16,128) flattened
        const int bx = blk & 15, bt = blk >> 4;
        const int kc = bx * 4 + (t >> 6);   // 0..63
        const float* src = st + (size_t)(bt * 16 + l16) * SD + kc * 32 + quad * 8;
        float4 v0 = *(const float4*)(src);
        float4 v1 = *(const float4*)(src + 4);
        ushort4 o0, o1;
        o0.x = f2bf(v0.x); o0.y = f2bf(v0.y); o0.z = f2bf(v0.z); o0.w = f2bf(v0.w);
        o1.x = f2bf(v1.x); o1.y = f2bf(v1.y); o1.z = f2bf(v1.z); o1.w = f2bf(v1.w);
        unsigned short* dst = stA + ((size_t)bt * 64 + kc) * 512 + l * 8;
        *(ushort4*)(dst)     = o0;
        *(ushort4*)(dst + 4) = o1;
    } else {                        // ---- wswz part: grid (72,32) flattened
        const int b2 = blk - 2048;
        const int bx = b2 % 72, i = b2 / 72;        // i = k-chunk 0..31
        const int f = bx * 2 + (t >> 7);            // frag 0..143
        const int h = (t >> 6) & 1;
        const int n = f * 16 + l16;

        const float* src; int ld, nr = 0;
        if (f < 128)      { src = Ww1; ld = 2048; nr = n; }
        else if (f < 132) { src = Wwf; ld = 64;   nr = n - 2048; }
        else if (f < 136) { src = Wb1; ld = 64;   nr = n - 2112; }
        else if (f < 140) { src = Wv1; ld = 64;   nr = n - 2176; }
        else              { src = nullptr; ld = 64; }

        const int k0 = i * 64 + h * 32 + quad * 8;
        unsigned short vals[8];
        #pragma unroll
        for (int j = 0; j < 8; j++)
            vals[j] = src ? f2bf(src[(size_t)(k0 + j) * ld + nr]) : (unsigned short)0;

        unsigned short* dst = Wswz + (((size_t)i * NFRG + f) * 2 + h) * 512 + l * 8;
        ushort4 o0 = {vals[0], vals[1], vals[2], vals[3]};
        ushort4 o1 = {vals[4], vals[5], vals[6], vals[7]};
        *(ushort4*)(dst)     = o0;
        *(ushort4*)(dst + 4) = o1;
    }
}

// ---------------- K1: Ycn = -(st @ Wcat + bias), LDS-staged tiles --------
// R5-proven 64x128 / 256-thread form. R6 (reg-stream A) and R10 (128x128
// 512-thread) BOTH regressed — R10 even poisoned the downstream k3 by
// ~23 us (cache/power state coupling). Do not change this kernel's shape.
__global__ __launch_bounds__(256) void k1_gemm(const unsigned short* __restrict__ stA,
                                               const unsigned short* __restrict__ Wswz,
                                               const float* __restrict__ bw1,
                                               const float* __restrict__ bwf,
                                               const float* __restrict__ bb1,
                                               const float* __restrict__ bv1,
                                               float* __restrict__ Ycn)
{
    const int t = threadIdx.x;
    const int m0t = blockIdx.x * 4;   // btile base (64 rows)
    const int n0f = blockIdx.y * 8;   // frag base (128 cols)
    const int wid = t >> 6, lane = t & 63;
    const int wm = wid & 1, wn = wid >> 1;
    const int l16 = lane & 15;

    __shared__ unsigned short As[2][2][4][512];   // [buf][kk][btile][512] = 16 KB
    __shared__ unsigned short Bs[2][2][8][512];   // [buf][kk][frag ][512] = 32 KB

    floatx4 acc[2][4];
    #pragma unroll
    for (int i = 0; i < 2; i++)
        #pragma unroll
        for (int j = 0; j < 4; j++) acc[i][j] = (floatx4)0.f;

    // stage iteration 'it' (kc = it*2, it*2+1) into buffer buf.
    // 24 chunks of 1 KB; this wave issues chunks c = wid*6 .. wid*6+5.
    auto stage = [&](int it, int buf) {
        #pragma unroll
        for (int j = 0; j < 6; j++) {
            const int c   = wid * 6 + j;        // 0..23
            const int kk  = c / 12;             // 0..1
            const int rem = c % 12;
            if (rem < 4) {
                const unsigned short* gp = stA
                    + ((size_t)(m0t + rem) * 64 + (it * 2 + kk)) * 512 + lane * 8;
                stage16(gp, &As[buf][kk][rem][0]);
            } else {
                const int f = rem - 4;          // 0..7
                const unsigned short* gp = Wswz
                    + (((size_t)it * NFRG + (n0f + f)) * 2 + kk) * 512 + lane * 8;
                stage16(gp, &Bs[buf][kk][f][0]);
            }
        }
    };

    stage(0, 0);
    __syncthreads();

    for (int it = 0; it < 32; it++) {
        const int buf = it & 1;
        if (it < 31) stage(it + 1, buf ^ 1);
        #pragma unroll
        for (int kk = 0; kk < 2; kk++) {
            bf16x8 a0 = *(const bf16x8*)&As[buf][kk][wm * 2 + 0][lane * 8];
            bf16x8 a1 = *(const bf16x8*)&As[buf][kk][wm * 2 + 1][lane * 8];
            bf16x8 b[4];
            #pragma unroll
            for (int nf = 0; nf < 4; nf++)
                b[nf] = *(const bf16x8*)&Bs[buf][kk][wn * 4 + nf][lane * 8];
            #pragma unroll
            for (int nf = 0; nf < 4; nf++) {
                acc[0][nf] = __builtin_amdgcn_mfma_f32_16x16x32_bf16(a0, b[nf], acc[0][nf], 0, 0, 0);
                acc[1][nf] = __builtin_amdgcn_mfma_f32_16x16x32_bf16(a1, b[nf], acc[1][nf], 0, 0, 0);
            }
        }
        __syncthreads();
    }

    #pragma unroll
    for (int mf = 0; mf < 2; mf++)
        #pragma unroll
        for (int nf = 0; nf < 4; nf++) {
            const int f  = n0f + wn * 4 + nf;
            const int bt = m0t + wm * 2 + mf;
            const int n  = f * 16 + l16;
            float bias;
            if (f < 128)      bias = bw1[n];
            else if (f < 132) bias = bwf[n - 2048];
            else if (f < 136) bias = bb1[n - 2112];
            else if (f < 140) bias = bv1[n - 2176];
            else              bias = 0.f;
            floatx4 o;
            #pragma unroll
            for (int r = 0; r < 4; r++) o[r] = -(acc[mf][nf][r] + bias);
            *(floatx4*)(Ycn + ((size_t)bt * NFRG + f) * 256 + lane * 4) = o;
        }
}

// ---------------- K3: q1[i][b] (+ q_tot on elected block), staged W ------
// R8-proven version (best total 180.0): mask-PAIR per block, 512 blocks,
// stage -> compute -> __syncthreads. Ledger: do NOT re-pipeline (R2-R4),
// do NOT split the pair (R9). Floor ~47-49 us in this decomposition.
// dotot election p == (btg & 15): bijective, XCD-spread (4 per XCD).
__global__ __launch_bounds__(256) void k3_q1(
    const unsigned short* __restrict__ stA, const float* __restrict__ qs,
    const unsigned short* __restrict__ Wswz, const float* __restrict__ Wv2,
    const float* __restrict__ bv2, const float* __restrict__ Ycn,
    float* __restrict__ q1, float* __restrict__ qtot)
{
    const int p   = blockIdx.x;          // mask pair: masks p, p+16
    const int btg = blockIdx.y;          // bt group of 4
    const int t = threadIdx.x;
    const int w = t >> 6, lane = t & 63;
    const int bt = btg * 4 + w;
    const int quad = lane >> 4, l16 = lane & 15;
    const int im[2] = { p, p + 16 };
    const bool dotot = (p == (btg & 15));

    __shared__ unsigned short Wl[2][2][4][2][512];  // [buf][mask][nf][half][512] = 32 KB
    __shared__ float qs_s[4][16][33];               // per-wave qs tile

    // qs into LDS (per wave)
    {
        int b = lane >> 2, a0 = (lane & 3) * 8;
        const float* src = qs + (size_t)(bt * 16 + b) * NA + a0;
        #pragma unroll
        for (int u = 0; u < 8; u++) qs_s[w][b][a0 + u] = src[u];
    }

    // A fragments (agent-i k-chunk of st) for both masks
    bf16x8 A0[2], A1[2];
    #pragma unroll
    for (int m = 0; m < 2; m++) {
        A0[m] = *(const bf16x8*)(stA + ((size_t)bt * 64 + 2 * im[m] + 0) * 512 + lane * 8);
        A1[m] = *(const bf16x8*)(stA + ((size_t)bt * 64 + 2 * im[m] + 1) * 512 + lane * 8);
    }

    const float* Yb = Ycn + (size_t)bt * NFRG * 256 + lane * 4;

    // stage frag-group fg (frags fg*4..fg*4+3, both masks) into buffer buf.
    auto stage = [&](int fg, int buf) {
        #pragma unroll
        for (int j = 0; j < 4; j++) {
            const int c  = w * 4 + j;          // 0..15
            const int m  = c >> 3;
            const int nf = (c >> 1) & 3;
            const int h  = c & 1;
            const unsigned short* g = Wswz
                + ((size_t)(im[m] * NFRG + fg * 4 + nf) * 2 + h) * 512 + lane * 8;
            stage16(g, &Wl[buf][m][nf][h][0]);
        }
    };

    floatx4 yv[4], yn[4], acc[2][4];

    auto wmfma = [&](int buf) {
        #pragma unroll
        for (int m = 0; m < 2; m++)
            #pragma unroll
            for (int nf = 0; nf < 4; nf++) {
                bf16x8 w0 = *(const bf16x8*)&Wl[buf][m][nf][0][lane * 8];
                bf16x8 w1 = *(const bf16x8*)&Wl[buf][m][nf][1][lane * 8];
                floatx4 a = __builtin_amdgcn_mfma_f32_16x16x32_bf16(A0[m], w0, yv[nf], 0, 0, 0);
                acc[m][nf] = __builtin_amdgcn_mfma_f32_16x16x32_bf16(A1[m], w1, a, 0, 0, 0);
            }
    };

    floatx4 hid[2][4];
    #pragma unroll
    for (int m = 0; m < 2; m++)
        #pragma unroll
        for (int nf = 0; nf < 4; nf++) hid[m][nf] = (floatx4)0.f;

    floatx4 hidT[4], wffT[4], b1fT[4], vaccT = (floatx4)0.f;
    #pragma unroll
    for (int nf = 0; nf < 4; nf++) hidT[nf] = (floatx4)0.f;

    // prologue: stage group 0, prefetch Ycn group 0
    stage(0, 0);
    #pragma unroll
    for (int nf = 0; nf < 4; nf++) yv[nf] = *(const floatx4*)(Yb + (size_t)nf * 256);
    __syncthreads();

    // main agent loop: groups 0..31 (agents)
    for (int fg = 0; fg < 32; fg++) {
        const int cur = fg & 1;
        stage(fg + 1, cur ^ 1);
        {
            const float* yp = Yb + (size_t)(fg + 1) * 4 * 256;
            #pragma unroll
            for (int nf = 0; nf < 4; nf++) yn[nf] = *(const floatx4*)(yp + (size_t)nf * 256);
        }
        wmfma(cur);
        float qv[4];
        #pragma unroll
        for (int r = 0; r < 4; r++) qv[r] = qs_s[w][quad * 4 + r][fg];
        #pragma unroll
        for (int m = 0; m < 2; m++)
            #pragma unroll
            for (int nf = 0; nf < 4; nf++)
                #pragma unroll
                for (int r = 0; r < 4; r++)
                    hid[m][nf][r] += qv[r] * fabsf(acc[m][nf][r]);
        if (dotot) {
            #pragma unroll
            for (int nf = 0; nf < 4; nf++)
                #pragma unroll
                for (int r = 0; r < 4; r++)
                    hidT[nf][r] += qv[r] * fabsf(yv[nf][r]);
        }
        #pragma unroll
        for (int nf = 0; nf < 4; nf++) yv[nf] = yn[nf];
        __syncthreads();
    }

    floatx4 wff[2][4], b1f[2][4], vacc[2];

    // group 32: wf frags (128..131)   [uses buf 0; fg=31 staged into buf 0]
    {
        stage(33, 1);
        {
            const float* yp = Yb + (size_t)33 * 4 * 256;
            #pragma unroll
            for (int nf = 0; nf < 4; nf++) yn[nf] = *(const floatx4*)(yp + (size_t)nf * 256);
        }
        wmfma(0);
        #pragma unroll
        for (int m = 0; m < 2; m++)
            #pragma unroll
            for (int nf = 0; nf < 4; nf++)
                #pragma unroll
                for (int r = 0; r < 4; r++) wff[m][nf][r] = fabsf(acc[m][nf][r]);
        if (dotot) {
            #pragma unroll
            for (int nf = 0; nf < 4; nf++)
                #pragma unroll
                for (int r = 0; r < 4; r++) wffT[nf][r] = fabsf(yv[nf][r]);
        }
        #pragma unroll
        for (int nf = 0; nf < 4; nf++) yv[nf] = yn[nf];
        __syncthreads();
    }
    // group 33: b1 frags (132..135)
    {
        stage(34, 0);
        {
            const float* yp = Yb + (size_t)34 * 4 * 256;
            #pragma unroll
            for (int nf = 0; nf < 4; nf++) yn[nf] = *(const floatx4*)(yp + (size_t)nf * 256);
        }
        wmfma(1);
        #pragma unroll
        for (int m = 0; m < 2; m++)
            #pragma unroll
            for (int nf = 0; nf < 4; nf++)
                #pragma unroll
                for (int r = 0; r < 4; r++) b1f[m][nf][r] = -acc[m][nf][r];
        if (dotot) {
            #pragma unroll
            for (int nf = 0; nf < 4; nf++)
                #pragma unroll
                for (int r = 0; r < 4; r++) b1fT[nf][r] = -yv[nf][r];
        }
        #pragma unroll
        for (int nf = 0; nf < 4; nf++) yv[nf] = yn[nf];
        __syncthreads();
    }
    // group 34: v frags (136..139)
    {
        wmfma(0);
        float wv2f[4];
        #pragma unroll
        for (int nf = 0; nf < 4; nf++) wv2f[nf] = Wv2[nf * 16 + l16];
        #pragma unroll
        for (int m = 0; m < 2; m++) {
            vacc[m] = (floatx4)0.f;
            #pragma unroll
            for (int nf = 0; nf < 4; nf++)
                #pragma unroll
                for (int r = 0; r < 4; r++)
                    vacc[m][r] += fmaxf(-acc[m][nf][r], 0.f) * wv2f[nf];
        }
        if (dotot) {
            #pragma unroll
            for (int nf = 0; nf < 4; nf++)
                #pragma unroll
                for (int r = 0; r < 4; r++)
                    vaccT[r] += fmaxf(-yv[nf][r], 0.f) * wv2f[nf];
        }
    }

    const float bv2v = bv2[0];
    #pragma unroll
    for (int m = 0; m < 2; m++)
        #pragma unroll
        for (int r = 0; r < 4; r++) {
            float s = vacc[m][r];
            #pragma unroll
            for (int nf = 0; nf < 4; nf++) {
                float h = hid[m][nf][r] + b1f[m][nf][r];
                h = h > 0.f ? h : expm1f(h);
                s += h * wff[m][nf][r];
            }
            s += __shfl_xor(s, 1); s += __shfl_xor(s, 2);
            s += __shfl_xor(s, 4); s += __shfl_xor(s, 8);
            if (l16 == 0) q1[(size_t)im[m] * BT + bt * 16 + quad * 4 + r] = s + bv2v;
        }

    if (dotot) {
        #pragma unroll
        for (int r = 0; r < 4; r++) {
            float s = vaccT[r];
            #pragma unroll
            for (int nf = 0; nf < 4; nf++) {
                float h = hidT[nf][r] + b1fT[nf][r];
                h = h > 0.f ? h : expm1f(h);
                s += h * wffT[nf][r];
            }
            s += __shfl_xor(s, 1); s += __shfl_xor(s, 2);
            s += __shfl_xor(s, 4); s += __shfl_xor(s, 8);
            if (l16 == 0) qtot[bt * 16 + quad * 4 + r] = s + bv2v;
        }
    }
}

// ---------------- K4: wc + final mix, e-SLICED (4 blocks per bt) ---------
// R12: old k4 was 128 blocks = 0.5 blocks/CU = 2 waves/CU — half the GPU
// idle, pure exposed L3 latency on the 17 MB Ycn sweep. The final mix
// out[b] = sum_e elu(hid+b1)*wf + v decomposes over e: block (bt, x)
// handles e-slice x*16..x*16+15 (reads only frag a*4+x per agent + its
// own tail frags) and atomicAdd's its partial into out (pre-set to bv2
// by k0). 512 blocks = 2 blocks/CU, 8 waves/CU; same total traffic.
// wc/qw is tiny and duplicated per slice.
__global__ __launch_bounds__(256) void k4_final(
    const float* __restrict__ qs, const float* __restrict__ Ycn,
    const float* __restrict__ q1, const float* __restrict__ qtot,
    const float* __restrict__ Wv2, float* __restrict__ out)
{
    const int bt = blockIdx.x;      // 0..127
    const int x  = blockIdx.y;      // e-slice 0..3
    __shared__ float qs_s[16][33];
    __shared__ float qw_s[16][33];
    __shared__ float hidp[4][16][17];
    __shared__ float wfb[16][17], b1b[16][17], vb[16][17];
    __shared__ float qt[16];

    const int t = threadIdx.x, w = t >> 6, lane = t & 63;
    const int quad = lane >> 4, l16 = lane & 15;

    {
        int l = t * 2;
        float2 v = *(const float2*)&qs[(size_t)(bt * 16 + (l >> 5)) * NA + (l & 31)];
        qs_s[l >> 5][(l & 31) + 0] = v.x;
        qs_s[l >> 5][(l & 31) + 1] = v.y;
    }
    if (t < 16) qt[t] = qtot[bt * 16 + t];

    const float* Yb = Ycn + (size_t)bt * NFRG * 256;

    // tail frags for slice x: wave 0 -> wf (128+x), 1 -> b1 (132+x),
    // 2 -> v (136+x); wave 3 idle here.
    if (w < 3) {
        const int f = 128 + w * 4 + x;
        floatx4 c = *(const floatx4*)(Yb + (size_t)f * 256 + lane * 4);
        #pragma unroll
        for (int r = 0; r < 4; r++) {
            const int b = quad * 4 + r;
            if (w == 0)      wfb[b][l16] = fabsf(c[r]);
            else if (w == 1) b1b[b][l16] = -c[r];
            else             vb[b][l16]  = fmaxf(-c[r], 0.f) * Wv2[x * 16 + l16];
        }
    }
    __syncthreads();

    // wc: thread (w,quad,l16) -> row rr = w*4+quad, agents 2*l16, 2*l16+1
    {
        const int rr = w * 4 + quad;
        float qtv = qt[rr];
        float d0 = fabsf(qtv - q1[(size_t)(2 * l16 + 0) * BT + bt * 16 + rr]);
        float d1 = fabsf(qtv - q1[(size_t)(2 * l16 + 1) * BT + bt * 16 + rr]);
        float ss = d0 * d0 + d1 * d1;
        ss += __shfl_xor(ss, 1); ss += __shfl_xor(ss, 2);
        ss += __shfl_xor(ss, 4); ss += __shfl_xor(ss, 8);
        float inv = 1.f / fmaxf(sqrtf(ss), 1e-12f);
        qw_s[rr][2 * l16 + 0] = qs_s[rr][2 * l16 + 0] * d0 * inv;
        qw_s[rr][2 * l16 + 1] = qs_s[rr][2 * l16 + 1] * d1 * inv;
    }
    __syncthreads();

    // pass 2 (slice): wave w sweeps agents w*8..w*8+7, frag a*4+x only
    floatx4 hid2 = (floatx4)0.f;
    #pragma unroll
    for (int ia = 0; ia < 8; ia++) {
        const int a = w * 8 + ia;
        floatx4 c = *(const floatx4*)(Yb + (size_t)(a * 4 + x) * 256 + lane * 4);
        #pragma unroll
        for (int r = 0; r < 4; r++)
            hid2[r] += qw_s[quad * 4 + r][a] * fabsf(c[r]);
    }
    #pragma unroll
    for (int r = 0; r < 4; r++)
        hidp[w][quad * 4 + r][l16] = hid2[r];
    __syncthreads();

    // final: wave w rows w*4..w*4+3; 16 cols (l16); quads redundant.
    #pragma unroll
    for (int bb = 0; bb < 4; bb++) {
        const int b = w * 4 + bb;
        float h = hidp[0][b][l16] + hidp[1][b][l16]
                + hidp[2][b][l16] + hidp[3][b][l16] + b1b[b][l16];
        h = h > 0.f ? h : expm1f(h);
        float val = h * wfb[b][l16] + vb[b][l16];
        val += __shfl_xor(val, 1); val += __shfl_xor(val, 2);
        val += __shfl_xor(val, 4); val += __shfl_xor(val, 8);
        if (lane == 0) atomicAdd(&out[bt * 16 + b], val);
    }
}

extern "C" void kernel_launch(void* const* d_in, const int* in_sizes, int n_in,
                              void* d_out, int out_size, void* d_ws, size_t ws_size,
                              hipStream_t stream) {
    const float* qs  = (const float*)d_in[0];
    const float* st  = (const float*)d_in[1];
    const float* Ww1 = (const float*)d_in[2];
    const float* bw1 = (const float*)d_in[3];
    const float* Wwf = (const float*)d_in[4];
    const float* bwf = (const float*)d_in[5];
    const float* Wb1 = (const float*)d_in[6];
    const float* bb1 = (const float*)d_in[7];
    const float* Wv1 = (const float*)d_in[8];
    const float* bv1 = (const float*)d_in[9];
    const float* Wv2 = (const float*)d_in[10];
    const float* bv2 = (const float*)d_in[11];
    float* out = (float*)d_out;

    // workspace (~37 MB, same footprint as proven layout; old bcat slot
    // (2304 f32) reused as qtot (2048 f32) — no footprint change)
    float* Ycn           = (float*)d_ws;                           // 128*144*256 f32 = 18.87 MB
    unsigned short* stA  = (unsigned short*)(Ycn + (size_t)128 * NFRG * 256); // 8.39 MB
    unsigned short* Wswz = stA + (size_t)SD * SD;                  // 32*144*1024 bf16 = 9.44 MB
    float* qtot          = (float*)(Wswz + (size_t)32 * NFRG * 1024); // 2048 f32 (ex-bcat slot)
    float* q1v           = qtot + NFRG * 16;                       // 32*2048 f32

    k0_prep<<<4353, 256, 0, stream>>>(st, stA, Ww1, Wwf, Wb1, Wv1, Wswz, bv2, out);

    k1_gemm<<<dim3(BT / 64, NFRG / 8), 256, 0, stream>>>(stA, Wswz, bw1, bwf, bb1, bv1, Ycn);
    k3_q1  <<<dim3(16, 32), 256, 0, stream>>>(stA, qs, Wswz, Wv2, bv2, Ycn, q1v, qtot);
    k4_final<<<dim3(BT / 16, 4), 256, 0, stream>>>(qs, Ycn, q1v, qtot, Wv2, out);
}